// Round 9
// baseline (616.856 us; speedup 1.0000x reference)
//
#include <hip/hip_runtime.h>
#include <hip/hip_bf16.h>

#define HF 128   // feature/hidden dim (F == H == 128)
#define BSH 8    // bucket shift: 256 nodes per bucket
#define BSZ 256
#define NBMAX 1024
#define FCAP 8192
#define HB 512   // histogram/bin blocks

typedef __attribute__((ext_vector_type(8))) short bf16x8;
typedef __attribute__((ext_vector_type(4))) float f32x4;
typedef __attribute__((ext_vector_type(2))) float f32x2;

__device__ inline float bflo(unsigned u) { return __uint_as_float(u << 16); }
__device__ inline float bfhi(unsigned u) { return __uint_as_float(u & 0xffff0000u); }
__device__ inline unsigned short f2bf(float f) {
    unsigned u = __float_as_uint(f);
    unsigned r = (u + 0x7fffu + ((u >> 16) & 1u)) >> 16;
    return (unsigned short)r;
}
__device__ inline unsigned pack2(float a, float b) {
    return (unsigned)f2bf(a) | ((unsigned)f2bf(b) << 16);
}
// pack 8 floats -> 8 fp8 e4m3 (uint2)
__device__ inline uint2 pk8_fp8(const float* v) {
    int a = __builtin_amdgcn_cvt_pk_fp8_f32(v[0], v[1], 0, 0);
    a = __builtin_amdgcn_cvt_pk_fp8_f32(v[2], v[3], a, 1);
    int b = __builtin_amdgcn_cvt_pk_fp8_f32(v[4], v[5], 0, 0);
    b = __builtin_amdgcn_cvt_pk_fp8_f32(v[6], v[7], b, 1);
    uint2 r; r.x = (unsigned)a; r.y = (unsigned)b;
    return r;
}

// ============ mega-init: cast_x(bf16+fp8) | cast_wt | hist | bounds | zero ===
// Weights are emitted in MFMA B-fragment order:
//   Wf[((nt*4+kk)*64 + lane)*8 + j] = W[(kk*32+quad*8+j)*128 + (nt*16+m)]
// with lane = quad*16+m, so the GEMM reads each fragment as a lane-contiguous
// 16B load (coalesced 1KB per wave instruction, L2-resident).
__global__ __launch_bounds__(256) void init_all(
    const float* __restrict__ x, unsigned short* __restrict__ xb,
    unsigned char* __restrict__ x8, unsigned char* __restrict__ h8,
    int castBlk, int nchunks,
    const float* __restrict__ w0, const float* __restrict__ w1,
    const float* __restrict__ w2, const float* __restrict__ w3,
    unsigned short* __restrict__ WtAll,
    const int* __restrict__ dst, int* __restrict__ tot, int E, int chunkH,
    const int* __restrict__ batch, int* __restrict__ gstart, int N, int Gn, int nBlocks,
    float* __restrict__ Szero, float* __restrict__ outm)
{
    __shared__ int lh[NBMAX];
    int b = blockIdx.x;
    int t = threadIdx.x;
    if (b < castBlk) {                       // ---- cast x -> bf16 + fp8
        int i = b * 256 + t;
        if (i < nchunks) {
            float4 a = ((const float4*)x)[2 * i];
            float4 c = ((const float4*)x)[2 * i + 1];
            uint4 o;
            o.x = pack2(a.x, a.y); o.y = pack2(a.z, a.w);
            o.z = pack2(c.x, c.y); o.w = pack2(c.z, c.w);
            ((uint4*)xb)[i] = o;
            float v[8] = {a.x, a.y, a.z, a.w, c.x, c.y, c.z, c.w};
            ((uint2*)x8)[i] = pk8_fp8(v);
        }
        return;
    }
    b -= castBlk;
    if (b < 4) {                             // ---- fragment-order cast weights
        const float* W = (b == 0) ? w0 : (b == 1) ? w1 : (b == 2) ? w2 : w3;
        unsigned short* O = WtAll + b * 16384;
        for (int idx = t; idx < 16384; idx += 256) {
            int j    = idx & 7;
            int lane = (idx >> 3) & 63;
            int fk   = idx >> 9;             // 0..31
            int kk = fk & 3, nt = fk >> 2;
            int m = lane & 15, quad = lane >> 4;
            int ncol = nt * 16 + m;
            int krow = kk * 32 + quad * 8 + j;
            O[idx] = f2bf(W[krow * 128 + ncol]);
        }
        return;
    }
    b -= 4;
    if (b < HB) {                            // ---- histogram partials -> global tot
        int NBl = (N + BSZ - 1) >> BSH;
        for (int i = t; i < NBl; i += 256) lh[i] = 0;
        __syncthreads();
        int beg = b * chunkH;
        int end = min(E, beg + chunkH);
        for (int e = beg + t; e < end; e += 256)
            atomicAdd(&lh[dst[e] >> BSH], 1);
        __syncthreads();
        for (int i = t; i < NBl; i += 256) {
            int c = lh[i];
            if (c) atomicAdd(&tot[i], c);
        }
        return;
    }
    b -= HB;
    if (b < nBlocks) {                       // ---- graph bounds
        int i = b * 256 + t;
        if (i >= N) return;
        int bi = batch[i];
        int bp = (i == 0) ? -1 : batch[i - 1];
        for (int g = bp + 1; g <= bi; g++) gstart[g] = i;
        if (i == N - 1)
            for (int g = bi + 1; g <= Gn; g++) gstart[g] = N;
        return;
    }
    if (t < 2 * HF) { Szero[t] = 0.f; Szero[t + 2 * HF] = 0.f; }
    if (t == 0) outm[0] = 0.f;
    // zero-pad row at index N for both fp8 tables (tail neighbors point here)
    if (t < 32) ((unsigned*)(x8 + (size_t)N * HF))[t] = 0u;
    else if (t < 64) ((unsigned*)(h8 + (size_t)N * HF))[t - 32] = 0u;
}

// ============ scan: bucket totals (tiny) -> boff/bcur ========================
__global__ void scanp(const int* __restrict__ tot, int* __restrict__ boff,
                      int* __restrict__ bcur, int NB, int E)
{
    __shared__ int part[256];
    int t = threadIdx.x;
    int v[4];
    int s = 0;
#pragma unroll
    for (int i = 0; i < 4; i++) {
        int idx = t * 4 + i;
        v[i] = (idx < NB) ? tot[idx] : 0;
        s += v[i];
    }
    part[t] = s;
    __syncthreads();
    for (int o = 1; o < 256; o <<= 1) {
        int y = (t >= o) ? part[t - o] : 0;
        __syncthreads();
        part[t] += y;
        __syncthreads();
    }
    int base = part[t] - s;
#pragma unroll
    for (int i = 0; i < 4; i++) {
        int idx = t * 4 + i;
        if (idx < NB) { boff[idx] = base; bcur[idx] = base; base += v[i]; }
    }
    if (t == 0) boff[NB] = E;
}

// ============ bin edges =====================================================
__global__ __launch_bounds__(256) void bucket_bin(
    const int* __restrict__ src, const int* __restrict__ dst,
    int* __restrict__ bcur, unsigned* __restrict__ ebuf, int E, int NB, int chunkH)
{
    __shared__ int lh[NBMAX];
    int t = threadIdx.x;
    for (int i = t; i < NB; i += 256) lh[i] = 0;
    __syncthreads();
    int beg = blockIdx.x * chunkH;
    int end = min(E, beg + chunkH);
    for (int e = beg + t; e < end; e += 256)
        atomicAdd(&lh[dst[e] >> BSH], 1);
    __syncthreads();
    for (int i = t; i < NB; i += 256) {
        int c = lh[i];
        lh[i] = c ? atomicAdd(&bcur[i], c) : 0;
    }
    __syncthreads();
    for (int e = beg + t; e < end; e += 256) {
        int d = dst[e];
        int b = d >> BSH;
        int pos = atomicAdd(&lh[b], 1);
        ebuf[pos] = ((unsigned)src[e] << BSH) | (unsigned)(d & (BSZ - 1));
    }
}

// ============ per-bucket fill ================================================
__global__ __launch_bounds__(256) void bucket_fill(
    const unsigned* __restrict__ ebuf, const int* __restrict__ boff,
    int* __restrict__ off, int* __restrict__ esrc, int N, int NB, int E)
{
    __shared__ int deg[BSZ];
    __shared__ int pref[BSZ];
    __shared__ int lcur[BSZ];
    __shared__ int lsr[FCAP];
    int b = blockIdx.x;
    int t = threadIdx.x;
    int segBeg = boff[b], segEnd = boff[b + 1];
    int segLen = segEnd - segBeg;
    int node0 = b << BSH;
    deg[t] = 0;
    __syncthreads();
    for (int i = segBeg + t; i < segEnd; i += 256)
        atomicAdd(&deg[ebuf[i] & (BSZ - 1)], 1);
    __syncthreads();
    int dv = deg[t];
    pref[t] = dv;
    __syncthreads();
    for (int o = 1; o < 256; o <<= 1) {
        int y = (t >= o) ? pref[t - o] : 0;
        __syncthreads();
        pref[t] += y;
        __syncthreads();
    }
    int excl = pref[t] - dv;
    int node = node0 + t;
    if (node < N) off[node] = segBeg + excl;
    lcur[t] = excl;
    if (b == NB - 1 && t == 0) off[N] = E;
    __syncthreads();
    if (segLen <= FCAP) {
        for (int i = segBeg + t; i < segEnd; i += 256) {
            unsigned v = ebuf[i];
            int slot = atomicAdd(&lcur[v & (BSZ - 1)], 1);
            lsr[slot] = (int)(v >> BSH);
        }
        __syncthreads();
        for (int i = t; i < segLen; i += 256) esrc[segBeg + i] = lsr[i];
    } else {
        for (int i = segBeg + t; i < segEnd; i += 256) {
            unsigned v = ebuf[i];
            int slot = atomicAdd(&lcur[v & (BSZ - 1)], 1);
            esrc[segBeg + slot] = (int)(v >> BSH);
        }
    }
}

// ============ gather: latency-bound random reads -> max occupancy ===========
// r8 showed gather is NOT VALU-bound (diet cut VALUBusy 59->42% with no
// speedup): it is bound by outstanding-request concurrency on the random
// 128B-row L2-miss path (2.3 TB/s at 46% occupancy, exactly our (256,4) cap).
// Fix: (256,8) -> 8 blocks/CU = 32 waves/CU (VGPR=48 < 64 so HW allows full
// occupancy). Double the in-flight loads, Little's-law the bandwidth up.
template <bool FOLD>
__global__ __launch_bounds__(256, 8) void gather_u(
    const unsigned short* __restrict__ xb, const unsigned char* __restrict__ x8,
    const int* __restrict__ off, const int* __restrict__ esrc,
    const float* __restrict__ epsp,
    const float* __restrict__ S1, const float* __restrict__ S2,
    const float* __restrict__ gamma, const float* __restrict__ beta, float invN,
    unsigned short* __restrict__ Uo, int N)
{
    __shared__ float lsc[HF], lsh[HF];
    int tid = threadIdx.x;
    if (FOLD) {
        if (tid < HF) {
            float mu = S1[tid] * invN;
            float var = S2[tid] * invN - mu * mu;
            float rs = rsqrtf(var + 1e-5f);
            float sc = gamma[tid] * rs;
            lsc[tid] = sc;
            lsh[tid] = beta[tid] - mu * sc;
        }
        __syncthreads();
    }
    int lane16 = tid & 15;
    int node = (blockIdx.x * 256 + tid) >> 4;
    if (node >= N) return;
    int beg = off[node], end = off[node + 1];
    float acc[8] = {0.f, 0.f, 0.f, 0.f, 0.f, 0.f, 0.f, 0.f};
    unsigned lofs = (unsigned)(lane16 * 8);
    for (int j0 = beg; j0 < end; j0 += 16) {
        int myidx = (j0 + lane16 < end) ? esrc[j0 + lane16] : N;  // N = zero row
        uint2 pb[16];
#pragma unroll
        for (int t = 0; t < 16; t++) {
            int s = __shfl(myidx, t, 16);
            unsigned voff = ((unsigned)s << 7) | lofs;
            pb[t] = *(const uint2*)(x8 + voff);
        }
#pragma unroll
        for (int t = 0; t < 16; t++) {
            f32x2 f0 = __builtin_amdgcn_cvt_pk_f32_fp8((int)pb[t].x, 0);
            f32x2 f1 = __builtin_amdgcn_cvt_pk_f32_fp8((int)pb[t].x, 1);
            f32x2 f2 = __builtin_amdgcn_cvt_pk_f32_fp8((int)pb[t].y, 0);
            f32x2 f3 = __builtin_amdgcn_cvt_pk_f32_fp8((int)pb[t].y, 1);
            acc[0] += f0.x; acc[1] += f0.y;
            acc[2] += f1.x; acc[3] += f1.y;
            acc[4] += f2.x; acc[5] += f2.y;
            acc[6] += f3.x; acc[7] += f3.y;
        }
    }
    float ep = 1.0f + epsp[0];
    uint4 xx = *(const uint4*)(xb + (size_t)node * HF + lane16 * 8);
    acc[0] += ep * bflo(xx.x); acc[1] += ep * bfhi(xx.x);
    acc[2] += ep * bflo(xx.y); acc[3] += ep * bfhi(xx.y);
    acc[4] += ep * bflo(xx.z); acc[5] += ep * bfhi(xx.z);
    acc[6] += ep * bflo(xx.w); acc[7] += ep * bfhi(xx.w);
    if (FOLD) {
        float cf = ep + (float)(end - beg);
        const float4 s0 = *(const float4*)(&lsc[lane16 * 8]);
        const float4 s1 = *(const float4*)(&lsc[lane16 * 8 + 4]);
        const float4 h0 = *(const float4*)(&lsh[lane16 * 8]);
        const float4 h1 = *(const float4*)(&lsh[lane16 * 8 + 4]);
        acc[0] = acc[0] * s0.x + h0.x * cf; acc[1] = acc[1] * s0.y + h0.y * cf;
        acc[2] = acc[2] * s0.z + h0.z * cf; acc[3] = acc[3] * s0.w + h0.w * cf;
        acc[4] = acc[4] * s1.x + h1.x * cf; acc[5] = acc[5] * s1.y + h1.y * cf;
        acc[6] = acc[6] * s1.z + h1.z * cf; acc[7] = acc[7] * s1.w + h1.w * cf;
    }
    uint4 o;
    o.x = pack2(acc[0], acc[1]); o.y = pack2(acc[2], acc[3]);
    o.z = pack2(acc[4], acc[5]); o.w = pack2(acc[6], acc[7]);
    *(uint4*)(Uo + (size_t)node * HF + lane16 * 8) = o;
}

// ====== persistent double-GEMM, REGISTER-RESIDENT weights ===================
// (round-6/7 structure: weights loaded once per block into registers; removed
// the 400MB/dispatch weight re-stream; gemm left top-5 at ~<40us. Unchanged.)
__global__ __launch_bounds__(256, 3) void gemm2L(
    const unsigned short* __restrict__ U,
    const unsigned short* __restrict__ Wfa, const float* __restrict__ ba,
    const unsigned short* __restrict__ Wfb, const float* __restrict__ bb,
    unsigned short* __restrict__ out, unsigned char* __restrict__ out8,
    float* __restrict__ S1, float* __restrict__ S2, int n)
{
    __shared__ __align__(16) unsigned short lA[2048];   // 4 KB h1 exchange (16x128 swz)
    __shared__ __align__(16) unsigned short lB[2048];   // 4 KB h2 staging
    int tid = threadIdx.x;
    int w = tid >> 6, lane = tid & 63;
    int m = lane & 15, quad = lane >> 4;
    int swzA = (m & 7) << 3;
    int ntiles = (n + 15) >> 4;

    // ---- resident weight fragments: wave w -> nt in {2w, 2w+1}
    const bf16x8* __restrict__ Ba = (const bf16x8*)Wfa;
    const bf16x8* __restrict__ Bb = (const bf16x8*)Wfb;
    bf16x8 wa[2][4], wb[2][4];
#pragma unroll
    for (int q = 0; q < 2; q++) {
        int nt = 2 * w + q;
#pragma unroll
        for (int kk = 0; kk < 4; kk++) {
            wa[q][kk] = Ba[(((nt << 2) | kk) << 6) | lane];
            wb[q][kk] = Bb[(((nt << 2) | kk) << 6) | lane];
        }
    }
    float bav[2], bbv[2];
#pragma unroll
    for (int q = 0; q < 2; q++) {
        bav[q] = ba[(2 * w + q) * 16 + m];
        bbv[q] = bb[(2 * w + q) * 16 + m];
    }
    float csA[2] = {0.f, 0.f}, cqA[2] = {0.f, 0.f};

    for (int tile = blockIdx.x; tile < ntiles; tile += gridDim.x) {
        int row0 = tile << 4;
        // ---- shared A fragments (all 4 waves load the same 16 rows; L1-served)
        int ar = row0 + m; if (ar >= n) ar = n - 1;
        const unsigned short* up = U + (size_t)ar * HF + quad * 8;
        bf16x8 aF[4];
#pragma unroll
        for (int kk = 0; kk < 4; kk++) aF[kk] = *(const bf16x8*)(up + kk * 32);

        // ---- GEMM1 quarter (8 MFMA)
        f32x4 acc[2];
#pragma unroll
        for (int q = 0; q < 2; q++) acc[q] = (f32x4){0.f, 0.f, 0.f, 0.f};
#pragma unroll
        for (int q = 0; q < 2; q++)
#pragma unroll
            for (int kk = 0; kk < 4; kk++)
                acc[q] = __builtin_amdgcn_mfma_f32_16x16x32_bf16(aF[kk], wa[q][kk], acc[q], 0, 0, 0);
        // relu+bias -> lA (column quarter, swizzled rows)
#pragma unroll
        for (int q = 0; q < 2; q++) {
            int col = (2 * w + q) * 16 + m;
#pragma unroll
            for (int r = 0; r < 4; r++) {
                int row = (quad << 2) | r;
                lA[(row << 7) | (col ^ ((row & 7) << 3))] =
                    f2bf(fmaxf(acc[q][r] + bav[q], 0.f));
            }
        }
        __syncthreads();
        // ---- full h1 rows for GEMM2 A-operand
        bf16x8 a2[4];
#pragma unroll
        for (int kk = 0; kk < 4; kk++)
            a2[kk] = *(const bf16x8*)(&lA[(m << 7) | (((kk << 5) | (quad << 3)) ^ swzA)]);
        // ---- GEMM2 quarter (8 MFMA)
#pragma unroll
        for (int q = 0; q < 2; q++) acc[q] = (f32x4){0.f, 0.f, 0.f, 0.f};
#pragma unroll
        for (int q = 0; q < 2; q++)
#pragma unroll
            for (int kk = 0; kk < 4; kk++)
                acc[q] = __builtin_amdgcn_mfma_f32_16x16x32_bf16(a2[kk], wb[q][kk], acc[q], 0, 0, 0);
        // ---- epilogue: relu+bias, reg-accumulated stats, restage to lB
#pragma unroll
        for (int q = 0; q < 2; q++) {
            int col = (2 * w + q) * 16 + m;
            float cs = 0.f, cq = 0.f;
#pragma unroll
            for (int r = 0; r < 4; r++) {
                int row = (quad << 2) | r;
                float v = fmaxf(acc[q][r] + bbv[q], 0.f);
                lB[(row << 7) | (col ^ ((row & 7) << 3))] = f2bf(v);
                if (row0 + row < n) { cs += v; cq += v * v; }
            }
            cs += __shfl_down(cs, 32); cs += __shfl_down(cs, 16);
            cq += __shfl_down(cq, 32); cq += __shfl_down(cq, 16);
            csA[q] += cs; cqA[q] += cq;
        }
        __syncthreads();
        // ---- coalesced store: 256 threads cover 16 rows x 16 chunks of 16B
        {
            int row = tid >> 4, c16 = tid & 15;
            int grow = row0 + row;
            if (grow < n) {
                uint4 v = *(const uint4*)(&lB[(row << 7) | ((c16 << 3) ^ ((row & 7) << 3))]);
                *(uint4*)(out + (size_t)grow * HF + (c16 << 3)) = v;
                if (out8) {
                    float f[8] = {bflo(v.x), bfhi(v.x), bflo(v.y), bfhi(v.y),
                                  bflo(v.z), bfhi(v.z), bflo(v.w), bfhi(v.w)};
                    *(uint2*)(out8 + (size_t)grow * HF + (c16 << 3)) = pk8_fp8(f);
                }
            }
        }
    }

    // ---- global stats: one atomic set per wave
    if (quad == 0) {
#pragma unroll
        for (int q = 0; q < 2; q++) {
            atomicAdd(&S1[(2 * w + q) * 16 + m], csA[q]);
            atomicAdd(&S2[(2 * w + q) * 16 + m], cqA[q]);
        }
    }
}

// ---- pool (BN2 inline) + lin1 + mse (atomic) + heads, one kernel/graph ----
__global__ __launch_bounds__(512) void pool_tail(
    const unsigned short* __restrict__ h2raw,
    const float* __restrict__ S1, const float* __restrict__ S2,
    const float* __restrict__ gamma, const float* __restrict__ beta, float invN,
    const int* __restrict__ gstart, const float* __restrict__ W,
    const float* __restrict__ bias,
    const float* __restrict__ Wloss, const float* __restrict__ blossp,
    const float* __restrict__ degree,
    const float* __restrict__ W2, const float* __restrict__ b2,
    const float* __restrict__ W4, const float* __restrict__ b4,
    float* __restrict__ out1, float* __restrict__ out3,
    float* __restrict__ outm, int C_, int D_)
{
    __shared__ float lsc[HF], lsh[HF];
    __shared__ float red[8][HF];
    __shared__ float gv[HF];
    __shared__ float part[4][HF];
    __shared__ float wred[8];
    __shared__ float zz[HF];
    __shared__ float logits[16];
    __shared__ float lse_s;
    int gid = blockIdx.x;
    int t = threadIdx.x;
    if (t < HF) {
        float mu = S1[t] * invN;
        float var = S2[t] * invN - mu * mu;
        float rs = rsqrtf(var + 1e-5f);
        float sc = gamma[t] * rs;
        lsc[t] = sc;
        lsh[t] = beta[t] - mu * sc;
    }
    __syncthreads();
    int c2 = t & 63;
    int rg = t >> 6;
    int b = gstart[gid], e = gstart[gid + 1];
    float wla = lsc[2 * c2] * Wloss[2 * c2];
    float wlb = lsc[2 * c2 + 1] * Wloss[2 * c2 + 1];
    float c0l = lsh[2 * c2] * Wloss[2 * c2] + lsh[2 * c2 + 1] * Wloss[2 * c2 + 1];
    float bl = blossp[0];
    float s0 = 0.f, s1 = 0.f, macc = 0.f;
    for (int r = b + rg; r < e; r += 8) {
        unsigned u = *(const unsigned*)(h2raw + (size_t)r * HF + c2 * 2);
        float v0 = bflo(u), v1 = bfhi(u);
        s0 += v0; s1 += v1;
        float m = v0 * wla + v1 * wlb + c0l;
#pragma unroll
        for (int o = 32; o > 0; o >>= 1) m += __shfl_down(m, o);
        if (c2 == 0) {
            float d = m + bl - degree[r];
            macc += d * d;
        }
    }
    red[rg][c2 * 2] = s0;
    red[rg][c2 * 2 + 1] = s1;
    if (c2 == 0) wred[rg] = macc;
    __syncthreads();
    if (t < HF) {
        float s = red[0][t] + red[1][t] + red[2][t] + red[3][t]
                + red[4][t] + red[5][t] + red[6][t] + red[7][t];
        gv[t] = (e > b) ? lsc[t] * (s / (float)(e - b)) + lsh[t] : 0.f;
    }
    __syncthreads();
    int c = t & 127, kg = t >> 7;
    float a = 0.f;
#pragma unroll 8
    for (int k = kg * 32; k < kg * 32 + 32; k++) a += gv[k] * W[(size_t)k * HF + c];
    part[kg][c] = a;
    __syncthreads();
    if (t < HF) {
        float aa = part[0][t] + part[1][t] + part[2][t] + part[3][t] + bias[t];
        zz[t] = fmaxf(aa, 0.f);
    }
    if (t == 0) {
        float ps = wred[0] + wred[1] + wred[2] + wred[3]
                 + wred[4] + wred[5] + wred[6] + wred[7];
        atomicAdd(outm, ps * invN);
    }
    __syncthreads();
    if (t < C_) {
        float aa = b2[t];
        for (int k = 0; k < HF; k++) aa += zz[k] * W2[(size_t)k * C_ + t];
        logits[t] = aa;
    }
    __syncthreads();
    if (t == 0) {
        float mx = -1e30f;
        for (int i = 0; i < C_; i++) mx = fmaxf(mx, logits[i]);
        float s = 0.f;
        for (int i = 0; i < C_; i++) s += expf(logits[i] - mx);
        lse_s = mx + logf(s);
    }
    __syncthreads();
    if (t < C_) out1[(size_t)gid * C_ + t] = logits[t] - lse_s;
    if (t < D_) {
        float aa = b4[t];
        for (int k = 0; k < HF; k++) aa += zz[k] * W4[(size_t)k * D_ + t];
        out3[(size_t)gid * D_ + t] = aa;
    }
}

extern "C" void kernel_launch(void* const* d_in, const int* in_sizes, int n_in,
                              void* d_out, int out_size, void* d_ws, size_t ws_size,
                              hipStream_t stream)
{
    const float* x      = (const float*)d_in[0];
    const int*   ei     = (const int*)d_in[1];
    const int*   batch  = (const int*)d_in[2];
    const float* degree = (const float*)d_in[3];
    const float* eps1   = (const float*)d_in[4];
    const float* W1a    = (const float*)d_in[5];
    const float* b1a    = (const float*)d_in[6];
    const float* W1b    = (const float*)d_in[7];
    const float* b1b    = (const float*)d_in[8];
    const float* g1     = (const float*)d_in[9];
    const float* be1    = (const float*)d_in[10];
    const float* eps2   = (const float*)d_in[11];
    const float* W2a    = (const float*)d_in[12];
    const float* b2a    = (const float*)d_in[13];
    const float* W2b    = (const float*)d_in[14];
    const float* b2b    = (const float*)d_in[15];
    const float* g2     = (const float*)d_in[16];
    const float* be2    = (const float*)d_in[17];
    const float* Wlin1  = (const float*)d_in[18];
    const float* blin1  = (const float*)d_in[19];
    const float* Wlin2  = (const float*)d_in[20];
    const float* blin2  = (const float*)d_in[21];
    const float* Wlin4  = (const float*)d_in[22];
    const float* blin4  = (const float*)d_in[23];
    const float* Wloss  = (const float*)d_in[24];
    const float* bloss  = (const float*)d_in[25];

    const int N  = in_sizes[0] / HF;
    const int E  = in_sizes[1] / 2;
    const int C_ = in_sizes[21];
    const int D_ = in_sizes[23];
    const int Gn = (out_size - 1) / (C_ + D_);
    const int NB = (N + BSZ - 1) >> BSH;

    const int* src = ei;
    const int* dst = ei + E;

    size_t NH = (size_t)N * HF;
    char* p = (char*)d_ws;
    unsigned short* xb  = (unsigned short*)p; p += NH * 2;
    unsigned short* U   = (unsigned short*)p; p += NH * 2;
    unsigned short* Hp1 = (unsigned short*)p; p += NH * 2;
    unsigned short* Hp2 = (unsigned short*)p; p += NH * 2;
    unsigned char*  x8  = (unsigned char*)p; p += NH + HF; // fp8 shadow of x (+zero row N)
    unsigned char*  h8  = (unsigned char*)p; p += NH + HF; // fp8 shadow of Hp1 (+zero row N)
    unsigned short* WtAll = (unsigned short*)p; p += 4 * 16384 * 2;
    float* S1a  = (float*)p; p += HF * 4;     // [S1a S2a S1b S2b] contiguous
    float* S2a  = (float*)p; p += HF * 4;
    float* S1b  = (float*)p; p += HF * 4;
    float* S2b  = (float*)p; p += HF * 4;
    int* gstart = (int*)p; p += (Gn + 1) * 4;
    int* boff   = (int*)p; p += (NBMAX + 1) * 4;
    int* bcur   = (int*)p; p += NBMAX * 4;
    int* tot    = (int*)p; p += NBMAX * 4;
    int* off    = (int*)p; p += (N + 1) * 4;
    int* esrc   = (int*)p; p += E * 4;
    unsigned* ebuf = (unsigned*)p; p += E * 4;

    unsigned short* Wt1a = WtAll;
    unsigned short* Wt1b = WtAll + 16384;
    unsigned short* Wt2a = WtAll + 32768;
    unsigned short* Wt2b = WtAll + 49152;

    float* out1 = (float*)d_out;
    float* out3 = out1 + (size_t)Gn * C_;
    float* outm = out3 + (size_t)Gn * D_;

    int nchunks  = (int)(NH / 8);
    int castBlk  = (nchunks + 255) / 256;
    int nBlocks  = (N + 255) / 256;
    int gatherBlk = (N * 16 + 255) / 256;
    int ntiles   = (N + 15) / 16;
    int gemmBlk  = 1024;                      // persistent, ~4 blocks/CU
    if (gemmBlk > ntiles) gemmBlk = ntiles;
    int chunkH   = (E + HB - 1) / HB;
    float invN = 1.0f / (float)N;

    int initBlk = castBlk + 4 + HB + nBlocks + 1;

    // 0. zero bucket totals (accumulated by init_all's histogram phase)
    hipMemsetAsync(tot, 0, (size_t)NB * sizeof(int), stream);
    // 1. mega-init
    init_all<<<initBlk, 256, 0, stream>>>(x, xb, x8, h8, castBlk, nchunks,
                                          W1a, W1b, W2a, W2b, WtAll,
                                          dst, tot, E, chunkH,
                                          batch, gstart, N, Gn, nBlocks,
                                          S1a, outm);
    // 2. bucket totals -> offsets + cursors (tiny scan)
    scanp<<<1, 256, 0, stream>>>(tot, boff, bcur, NB, E);
    // 3. bin edges
    bucket_bin<<<HB, 256, 0, stream>>>(src, dst, bcur, ebuf, E, NB, chunkH);
    // 4. per-bucket CSR fill
    bucket_fill<<<NB, 256, 0, stream>>>(ebuf, boff, off, esrc, N, NB, E);
    // 5-6. layer 1 (high-occupancy gather from fp8 x8; gemm emits Hp1 + h8)
    gather_u<false><<<gatherBlk, 256, 0, stream>>>(xb, x8, off, esrc, eps1,
                                                   nullptr, nullptr, nullptr, nullptr, 0.f, U, N);
    gemm2L<<<gemmBlk, 256, 0, stream>>>(U, Wt1a, b1a, Wt1b, b1b, Hp1, h8, S1a, S2a, N);
    // 7-8. layer 2 (high-occupancy gather from fp8 h8; BN1 finalize inline)
    gather_u<true><<<gatherBlk, 256, 0, stream>>>(Hp1, h8, off, esrc, eps2,
                                                  S1a, S2a, g1, be1, invN, U, N);
    gemm2L<<<gemmBlk, 256, 0, stream>>>(U, Wt2a, b2a, Wt2b, b2b, Hp2, nullptr, S1b, S2b, N);
    // 9. tail
    pool_tail<<<Gn, 512, 0, stream>>>(Hp2, S1b, S2b, g2, be2, invN, gstart,
                                      Wlin1, blin1, Wloss, bloss, degree,
                                      Wlin2, blin2, Wlin4, blin4,
                                      out1, out3, outm, C_, D_);
}

// Round 11
// 433.713 us; speedup vs baseline: 1.4223x; 1.4223x over previous
//
#include <hip/hip_runtime.h>
#include <hip/hip_bf16.h>

#define HF 128   // feature/hidden dim (F == H == 128)
#define BSH 8    // bucket shift: 256 nodes per bucket
#define BSZ 256
#define NBMAX 1024
#define FCAP 8192
#define HB 512   // histogram/bin blocks

typedef __attribute__((ext_vector_type(8))) short bf16x8;
typedef __attribute__((ext_vector_type(4))) float f32x4;
typedef __attribute__((ext_vector_type(2))) float f32x2;

__device__ inline float bflo(unsigned u) { return __uint_as_float(u << 16); }
__device__ inline float bfhi(unsigned u) { return __uint_as_float(u & 0xffff0000u); }
__device__ inline unsigned short f2bf(float f) {
    unsigned u = __float_as_uint(f);
    unsigned r = (u + 0x7fffu + ((u >> 16) & 1u)) >> 16;
    return (unsigned short)r;
}
__device__ inline unsigned pack2(float a, float b) {
    return (unsigned)f2bf(a) | ((unsigned)f2bf(b) << 16);
}
// pack 8 floats -> 8 fp8 e4m3 (uint2)
__device__ inline uint2 pk8_fp8(const float* v) {
    int a = __builtin_amdgcn_cvt_pk_fp8_f32(v[0], v[1], 0, 0);
    a = __builtin_amdgcn_cvt_pk_fp8_f32(v[2], v[3], a, 1);
    int b = __builtin_amdgcn_cvt_pk_fp8_f32(v[4], v[5], 0, 0);
    b = __builtin_amdgcn_cvt_pk_fp8_f32(v[6], v[7], b, 1);
    uint2 r; r.x = (unsigned)a; r.y = (unsigned)b;
    return r;
}

// ============ mega-init: cast_x(bf16+fp8) | cast_wt | hist | bounds | zero ===
__global__ __launch_bounds__(256) void init_all(
    const float* __restrict__ x, unsigned short* __restrict__ xb,
    unsigned char* __restrict__ x8, unsigned char* __restrict__ h8,
    int castBlk, int nchunks,
    const float* __restrict__ w0, const float* __restrict__ w1,
    const float* __restrict__ w2, const float* __restrict__ w3,
    unsigned short* __restrict__ WtAll,
    const int* __restrict__ dst, int* __restrict__ tot, int E, int chunkH,
    const int* __restrict__ batch, int* __restrict__ gstart, int N, int Gn, int nBlocks,
    float* __restrict__ Szero, float* __restrict__ outm)
{
    __shared__ int lh[NBMAX];
    int b = blockIdx.x;
    int t = threadIdx.x;
    if (b < castBlk) {                       // ---- cast x -> bf16 + fp8
        int i = b * 256 + t;
        if (i < nchunks) {
            float4 a = ((const float4*)x)[2 * i];
            float4 c = ((const float4*)x)[2 * i + 1];
            uint4 o;
            o.x = pack2(a.x, a.y); o.y = pack2(a.z, a.w);
            o.z = pack2(c.x, c.y); o.w = pack2(c.z, c.w);
            ((uint4*)xb)[i] = o;
            float v[8] = {a.x, a.y, a.z, a.w, c.x, c.y, c.z, c.w};
            ((uint2*)x8)[i] = pk8_fp8(v);
        }
        return;
    }
    b -= castBlk;
    if (b < 4) {                             // ---- fragment-order cast weights
        const float* W = (b == 0) ? w0 : (b == 1) ? w1 : (b == 2) ? w2 : w3;
        unsigned short* O = WtAll + b * 16384;
        for (int idx = t; idx < 16384; idx += 256) {
            int j    = idx & 7;
            int lane = (idx >> 3) & 63;
            int fk   = idx >> 9;             // 0..31
            int kk = fk & 3, nt = fk >> 2;
            int m = lane & 15, quad = lane >> 4;
            int ncol = nt * 16 + m;
            int krow = kk * 32 + quad * 8 + j;
            O[idx] = f2bf(W[krow * 128 + ncol]);
        }
        return;
    }
    b -= 4;
    if (b < HB) {                            // ---- histogram partials -> global tot
        int NBl = (N + BSZ - 1) >> BSH;
        for (int i = t; i < NBl; i += 256) lh[i] = 0;
        __syncthreads();
        int beg = b * chunkH;
        int end = min(E, beg + chunkH);
        for (int e = beg + t; e < end; e += 256)
            atomicAdd(&lh[dst[e] >> BSH], 1);
        __syncthreads();
        for (int i = t; i < NBl; i += 256) {
            int c = lh[i];
            if (c) atomicAdd(&tot[i], c);
        }
        return;
    }
    b -= HB;
    if (b < nBlocks) {                       // ---- graph bounds
        int i = b * 256 + t;
        if (i >= N) return;
        int bi = batch[i];
        int bp = (i == 0) ? -1 : batch[i - 1];
        for (int g = bp + 1; g <= bi; g++) gstart[g] = i;
        if (i == N - 1)
            for (int g = bi + 1; g <= Gn; g++) gstart[g] = N;
        return;
    }
    if (t < 2 * HF) { Szero[t] = 0.f; Szero[t + 2 * HF] = 0.f; }
    if (t == 0) outm[0] = 0.f;
    // zero-pad row at index N for both fp8 tables (harmless; kept for safety)
    if (t < 32) ((unsigned*)(x8 + (size_t)N * HF))[t] = 0u;
    else if (t < 64) ((unsigned*)(h8 + (size_t)N * HF))[t - 32] = 0u;
}

// ============ scan: bucket totals (tiny) -> boff/bcur ========================
__global__ void scanp(const int* __restrict__ tot, int* __restrict__ boff,
                      int* __restrict__ bcur, int NB, int E)
{
    __shared__ int part[256];
    int t = threadIdx.x;
    int v[4];
    int s = 0;
#pragma unroll
    for (int i = 0; i < 4; i++) {
        int idx = t * 4 + i;
        v[i] = (idx < NB) ? tot[idx] : 0;
        s += v[i];
    }
    part[t] = s;
    __syncthreads();
    for (int o = 1; o < 256; o <<= 1) {
        int y = (t >= o) ? part[t - o] : 0;
        __syncthreads();
        part[t] += y;
        __syncthreads();
    }
    int base = part[t] - s;
#pragma unroll
    for (int i = 0; i < 4; i++) {
        int idx = t * 4 + i;
        if (idx < NB) { boff[idx] = base; bcur[idx] = base; base += v[i]; }
    }
    if (t == 0) boff[NB] = E;
}

// ============ bin edges =====================================================
__global__ __launch_bounds__(256) void bucket_bin(
    const int* __restrict__ src, const int* __restrict__ dst,
    int* __restrict__ bcur, unsigned* __restrict__ ebuf, int E, int NB, int chunkH)
{
    __shared__ int lh[NBMAX];
    int t = threadIdx.x;
    for (int i = t; i < NB; i += 256) lh[i] = 0;
    __syncthreads();
    int beg = blockIdx.x * chunkH;
    int end = min(E, beg + chunkH);
    for (int e = beg + t; e < end; e += 256)
        atomicAdd(&lh[dst[e] >> BSH], 1);
    __syncthreads();
    for (int i = t; i < NB; i += 256) {
        int c = lh[i];
        lh[i] = c ? atomicAdd(&bcur[i], c) : 0;
    }
    __syncthreads();
    for (int e = beg + t; e < end; e += 256) {
        int d = dst[e];
        int b = d >> BSH;
        int pos = atomicAdd(&lh[b], 1);
        ebuf[pos] = ((unsigned)src[e] << BSH) | (unsigned)(d & (BSZ - 1));
    }
}

// ============ per-bucket fill ================================================
__global__ __launch_bounds__(256) void bucket_fill(
    const unsigned* __restrict__ ebuf, const int* __restrict__ boff,
    int* __restrict__ off, int* __restrict__ esrc, int N, int NB, int E)
{
    __shared__ int deg[BSZ];
    __shared__ int pref[BSZ];
    __shared__ int lcur[BSZ];
    __shared__ int lsr[FCAP];
    int b = blockIdx.x;
    int t = threadIdx.x;
    int segBeg = boff[b], segEnd = boff[b + 1];
    int segLen = segEnd - segBeg;
    int node0 = b << BSH;
    deg[t] = 0;
    __syncthreads();
    for (int i = segBeg + t; i < segEnd; i += 256)
        atomicAdd(&deg[ebuf[i] & (BSZ - 1)], 1);
    __syncthreads();
    int dv = deg[t];
    pref[t] = dv;
    __syncthreads();
    for (int o = 1; o < 256; o <<= 1) {
        int y = (t >= o) ? pref[t - o] : 0;
        __syncthreads();
        pref[t] += y;
        __syncthreads();
    }
    int excl = pref[t] - dv;
    int node = node0 + t;
    if (node < N) off[node] = segBeg + excl;
    lcur[t] = excl;
    if (b == NB - 1 && t == 0) off[N] = E;
    __syncthreads();
    if (segLen <= FCAP) {
        for (int i = segBeg + t; i < segEnd; i += 256) {
            unsigned v = ebuf[i];
            int slot = atomicAdd(&lcur[v & (BSZ - 1)], 1);
            lsr[slot] = (int)(v >> BSH);
        }
        __syncthreads();
        for (int i = t; i < segLen; i += 256) esrc[segBeg + i] = lsr[i];
    } else {
        for (int i = segBeg + t; i < segEnd; i += 256) {
            unsigned v = ebuf[i];
            int slot = atomicAdd(&lcur[v & (BSZ - 1)], 1);
            esrc[segBeg + slot] = (int)(v >> BSH);
        }
    }
}

// ============ gather: pipelined neighbor loads from fp8 table ===============
// Round-7 body (measured best: 48.2us): 16-deep load batch into registers,
// cndmask tail-zeroing, (256,4). r8 diet regressed 9%; r9 (256,8) spilled.
template <bool FOLD>
__global__ __launch_bounds__(256, 4) void gather_u(
    const unsigned short* __restrict__ xb, const unsigned char* __restrict__ x8,
    const int* __restrict__ off, const int* __restrict__ esrc,
    const float* __restrict__ epsp,
    const float* __restrict__ S1, const float* __restrict__ S2,
    const float* __restrict__ gamma, const float* __restrict__ beta, float invN,
    unsigned short* __restrict__ Uo, int N)
{
    __shared__ float lsc[HF], lsh[HF];
    int tid = threadIdx.x;
    if (FOLD) {
        if (tid < HF) {
            float mu = S1[tid] * invN;
            float var = S2[tid] * invN - mu * mu;
            float rs = rsqrtf(var + 1e-5f);
            float sc = gamma[tid] * rs;
            lsc[tid] = sc;
            lsh[tid] = beta[tid] - mu * sc;
        }
        __syncthreads();
    }
    int lane16 = tid & 15;
    int node = (blockIdx.x * 256 + tid) >> 4;
    if (node >= N) return;
    int beg = off[node], end = off[node + 1];
    float acc[8] = {0.f, 0.f, 0.f, 0.f, 0.f, 0.f, 0.f, 0.f};
    const unsigned char* x8l = x8 + lane16 * 8;
    for (int j0 = beg; j0 < end; j0 += 16) {
        int myidx = (j0 + lane16 < end) ? esrc[j0 + lane16] : -1;
        uint2 pb[16];
#pragma unroll
        for (int t = 0; t < 16; t++) {
            int s = __shfl(myidx, t, 16);
            int sc = (s < 0) ? 0 : s;
            uint2 pv = *(const uint2*)(x8l + (size_t)sc * HF);
            if (s < 0) { pv.x = 0u; pv.y = 0u; }
            pb[t] = pv;
        }
#pragma unroll
        for (int t = 0; t < 16; t++) {
            f32x2 f0 = __builtin_amdgcn_cvt_pk_f32_fp8((int)pb[t].x, 0);
            f32x2 f1 = __builtin_amdgcn_cvt_pk_f32_fp8((int)pb[t].x, 1);
            f32x2 f2 = __builtin_amdgcn_cvt_pk_f32_fp8((int)pb[t].y, 0);
            f32x2 f3 = __builtin_amdgcn_cvt_pk_f32_fp8((int)pb[t].y, 1);
            acc[0] += f0.x; acc[1] += f0.y;
            acc[2] += f1.x; acc[3] += f1.y;
            acc[4] += f2.x; acc[5] += f2.y;
            acc[6] += f3.x; acc[7] += f3.y;
        }
    }
    float ep = 1.0f + epsp[0];
    uint4 xx = *(const uint4*)(xb + (size_t)node * HF + lane16 * 8);
    acc[0] += ep * bflo(xx.x); acc[1] += ep * bfhi(xx.x);
    acc[2] += ep * bflo(xx.y); acc[3] += ep * bfhi(xx.y);
    acc[4] += ep * bflo(xx.z); acc[5] += ep * bfhi(xx.z);
    acc[6] += ep * bflo(xx.w); acc[7] += ep * bfhi(xx.w);
    if (FOLD) {
        float cf = ep + (float)(end - beg);
        const float4 s0 = *(const float4*)(&lsc[lane16 * 8]);
        const float4 s1 = *(const float4*)(&lsc[lane16 * 8 + 4]);
        const float4 h0 = *(const float4*)(&lsh[lane16 * 8]);
        const float4 h1 = *(const float4*)(&lsh[lane16 * 8 + 4]);
        acc[0] = acc[0] * s0.x + h0.x * cf; acc[1] = acc[1] * s0.y + h0.y * cf;
        acc[2] = acc[2] * s0.z + h0.z * cf; acc[3] = acc[3] * s0.w + h0.w * cf;
        acc[4] = acc[4] * s1.x + h1.x * cf; acc[5] = acc[5] * s1.y + h1.y * cf;
        acc[6] = acc[6] * s1.z + h1.z * cf; acc[7] = acc[7] * s1.w + h1.w * cf;
    }
    uint4 o;
    o.x = pack2(acc[0], acc[1]); o.y = pack2(acc[2], acc[3]);
    o.z = pack2(acc[4], acc[5]); o.w = pack2(acc[6], acc[7]);
    *(uint4*)(Uo + (size_t)node * HF + lane16 * 8) = o;
}

// ====== persistent double-GEMM, REGISTER-RESIDENT weights + A prefetch ======
// Weights held in registers once per block (r7: removed 400MB weight
// re-stream, 66->~45us). This round: software-pipeline the A-tile loads —
// next tile's fragments (aN) are issued BEFORE the current tile's GEMMs, so
// the ~200-300cy L2 latency hides under GEMM1+GEMM2+barriers. (+16 VGPR,
// ~140 total, within the (256,3) cap.)
__global__ __launch_bounds__(256, 3) void gemm2L(
    const unsigned short* __restrict__ U,
    const unsigned short* __restrict__ Wfa, const float* __restrict__ ba,
    const unsigned short* __restrict__ Wfb, const float* __restrict__ bb,
    unsigned short* __restrict__ out, unsigned char* __restrict__ out8,
    float* __restrict__ S1, float* __restrict__ S2, int n)
{
    __shared__ __align__(16) unsigned short lA[2048];   // 4 KB h1 exchange (16x128 swz)
    __shared__ __align__(16) unsigned short lB[2048];   // 4 KB h2 staging
    int tid = threadIdx.x;
    int w = tid >> 6, lane = tid & 63;
    int m = lane & 15, quad = lane >> 4;
    int swzA = (m & 7) << 3;
    int ntiles = (n + 15) >> 4;

    // ---- resident weight fragments: wave w -> nt in {2w, 2w+1}
    const bf16x8* __restrict__ Ba = (const bf16x8*)Wfa;
    const bf16x8* __restrict__ Bb = (const bf16x8*)Wfb;
    bf16x8 wa[2][4], wb[2][4];
#pragma unroll
    for (int q = 0; q < 2; q++) {
        int nt = 2 * w + q;
#pragma unroll
        for (int kk = 0; kk < 4; kk++) {
            wa[q][kk] = Ba[(((nt << 2) | kk) << 6) | lane];
            wb[q][kk] = Bb[(((nt << 2) | kk) << 6) | lane];
        }
    }
    float bav[2], bbv[2];
#pragma unroll
    for (int q = 0; q < 2; q++) {
        bav[q] = ba[(2 * w + q) * 16 + m];
        bbv[q] = bb[(2 * w + q) * 16 + m];
    }
    float csA[2] = {0.f, 0.f}, cqA[2] = {0.f, 0.f};

    // ---- prologue: load first tile's A fragments
    bf16x8 aF[4];
    int tile = blockIdx.x;
    if (tile < ntiles) {
        int ar = tile * 16 + m; if (ar >= n) ar = n - 1;
        const unsigned short* up = U + (size_t)ar * HF + quad * 8;
#pragma unroll
        for (int kk = 0; kk < 4; kk++) aF[kk] = *(const bf16x8*)(up + kk * 32);
    }

    for (; tile < ntiles; tile += gridDim.x) {
        int row0 = tile << 4;
        // ---- prefetch next tile's A fragments (reload current on last iter)
        bf16x8 aN[4];
        {
            int tn = tile + gridDim.x;
            int tl = (tn < ntiles) ? tn : tile;
            int ar = tl * 16 + m; if (ar >= n) ar = n - 1;
            const unsigned short* up = U + (size_t)ar * HF + quad * 8;
#pragma unroll
            for (int kk = 0; kk < 4; kk++) aN[kk] = *(const bf16x8*)(up + kk * 32);
        }

        // ---- GEMM1 quarter (8 MFMA)
        f32x4 acc[2];
#pragma unroll
        for (int q = 0; q < 2; q++) acc[q] = (f32x4){0.f, 0.f, 0.f, 0.f};
#pragma unroll
        for (int q = 0; q < 2; q++)
#pragma unroll
            for (int kk = 0; kk < 4; kk++)
                acc[q] = __builtin_amdgcn_mfma_f32_16x16x32_bf16(aF[kk], wa[q][kk], acc[q], 0, 0, 0);
        // relu+bias -> lA (column quarter, swizzled rows)
#pragma unroll
        for (int q = 0; q < 2; q++) {
            int col = (2 * w + q) * 16 + m;
#pragma unroll
            for (int r = 0; r < 4; r++) {
                int row = (quad << 2) | r;
                lA[(row << 7) | (col ^ ((row & 7) << 3))] =
                    f2bf(fmaxf(acc[q][r] + bav[q], 0.f));
            }
        }
        __syncthreads();
        // ---- full h1 rows for GEMM2 A-operand
        bf16x8 a2[4];
#pragma unroll
        for (int kk = 0; kk < 4; kk++)
            a2[kk] = *(const bf16x8*)(&lA[(m << 7) | (((kk << 5) | (quad << 3)) ^ swzA)]);
        // ---- GEMM2 quarter (8 MFMA)
#pragma unroll
        for (int q = 0; q < 2; q++) acc[q] = (f32x4){0.f, 0.f, 0.f, 0.f};
#pragma unroll
        for (int q = 0; q < 2; q++)
#pragma unroll
            for (int kk = 0; kk < 4; kk++)
                acc[q] = __builtin_amdgcn_mfma_f32_16x16x32_bf16(a2[kk], wb[q][kk], acc[q], 0, 0, 0);
        // ---- epilogue: relu+bias, reg-accumulated stats, restage to lB
#pragma unroll
        for (int q = 0; q < 2; q++) {
            int col = (2 * w + q) * 16 + m;
            float cs = 0.f, cq = 0.f;
#pragma unroll
            for (int r = 0; r < 4; r++) {
                int row = (quad << 2) | r;
                float v = fmaxf(acc[q][r] + bbv[q], 0.f);
                lB[(row << 7) | (col ^ ((row & 7) << 3))] = f2bf(v);
                if (row0 + row < n) { cs += v; cq += v * v; }
            }
            cs += __shfl_down(cs, 32); cs += __shfl_down(cs, 16);
            cq += __shfl_down(cq, 32); cq += __shfl_down(cq, 16);
            csA[q] += cs; cqA[q] += cq;
        }
        __syncthreads();
        // ---- coalesced store: 256 threads cover 16 rows x 16 chunks of 16B
        {
            int row = tid >> 4, c16 = tid & 15;
            int grow = row0 + row;
            if (grow < n) {
                uint4 v = *(const uint4*)(&lB[(row << 7) | ((c16 << 3) ^ ((row & 7) << 3))]);
                *(uint4*)(out + (size_t)grow * HF + (c16 << 3)) = v;
                if (out8) {
                    float f[8] = {bflo(v.x), bfhi(v.x), bflo(v.y), bfhi(v.y),
                                  bflo(v.z), bfhi(v.z), bflo(v.w), bfhi(v.w)};
                    *(uint2*)(out8 + (size_t)grow * HF + (c16 << 3)) = pk8_fp8(f);
                }
            }
        }
#pragma unroll
        for (int kk = 0; kk < 4; kk++) aF[kk] = aN[kk];
    }

    // ---- global stats: one atomic set per wave
    if (quad == 0) {
#pragma unroll
        for (int q = 0; q < 2; q++) {
            atomicAdd(&S1[(2 * w + q) * 16 + m], csA[q]);
            atomicAdd(&S2[(2 * w + q) * 16 + m], cqA[q]);
        }
    }
}

// ---- pool (BN2 inline) + lin1 + mse (atomic) + heads, one kernel/graph ----
__global__ __launch_bounds__(512) void pool_tail(
    const unsigned short* __restrict__ h2raw,
    const float* __restrict__ S1, const float* __restrict__ S2,
    const float* __restrict__ gamma, const float* __restrict__ beta, float invN,
    const int* __restrict__ gstart, const float* __restrict__ W,
    const float* __restrict__ bias,
    const float* __restrict__ Wloss, const float* __restrict__ blossp,
    const float* __restrict__ degree,
    const float* __restrict__ W2, const float* __restrict__ b2,
    const float* __restrict__ W4, const float* __restrict__ b4,
    float* __restrict__ out1, float* __restrict__ out3,
    float* __restrict__ outm, int C_, int D_)
{
    __shared__ float lsc[HF], lsh[HF];
    __shared__ float red[8][HF];
    __shared__ float gv[HF];
    __shared__ float part[4][HF];
    __shared__ float wred[8];
    __shared__ float zz[HF];
    __shared__ float logits[16];
    __shared__ float lse_s;
    int gid = blockIdx.x;
    int t = threadIdx.x;
    if (t < HF) {
        float mu = S1[t] * invN;
        float var = S2[t] * invN - mu * mu;
        float rs = rsqrtf(var + 1e-5f);
        float sc = gamma[t] * rs;
        lsc[t] = sc;
        lsh[t] = beta[t] - mu * sc;
    }
    __syncthreads();
    int c2 = t & 63;
    int rg = t >> 6;
    int b = gstart[gid], e = gstart[gid + 1];
    float wla = lsc[2 * c2] * Wloss[2 * c2];
    float wlb = lsc[2 * c2 + 1] * Wloss[2 * c2 + 1];
    float c0l = lsh[2 * c2] * Wloss[2 * c2] + lsh[2 * c2 + 1] * Wloss[2 * c2 + 1];
    float bl = blossp[0];
    float s0 = 0.f, s1 = 0.f, macc = 0.f;
    for (int r = b + rg; r < e; r += 8) {
        unsigned u = *(const unsigned*)(h2raw + (size_t)r * HF + c2 * 2);
        float v0 = bflo(u), v1 = bfhi(u);
        s0 += v0; s1 += v1;
        float m = v0 * wla + v1 * wlb + c0l;
#pragma unroll
        for (int o = 32; o > 0; o >>= 1) m += __shfl_down(m, o);
        if (c2 == 0) {
            float d = m + bl - degree[r];
            macc += d * d;
        }
    }
    red[rg][c2 * 2] = s0;
    red[rg][c2 * 2 + 1] = s1;
    if (c2 == 0) wred[rg] = macc;
    __syncthreads();
    if (t < HF) {
        float s = red[0][t] + red[1][t] + red[2][t] + red[3][t]
                + red[4][t] + red[5][t] + red[6][t] + red[7][t];
        gv[t] = (e > b) ? lsc[t] * (s / (float)(e - b)) + lsh[t] : 0.f;
    }
    __syncthreads();
    int c = t & 127, kg = t >> 7;
    float a = 0.f;
#pragma unroll 8
    for (int k = kg * 32; k < kg * 32 + 32; k++) a += gv[k] * W[(size_t)k * HF + c];
    part[kg][c] = a;
    __syncthreads();
    if (t < HF) {
        float aa = part[0][t] + part[1][t] + part[2][t] + part[3][t] + bias[t];
        zz[t] = fmaxf(aa, 0.f);
    }
    if (t == 0) {
        float ps = wred[0] + wred[1] + wred[2] + wred[3]
                 + wred[4] + wred[5] + wred[6] + wred[7];
        atomicAdd(outm, ps * invN);
    }
    __syncthreads();
    if (t < C_) {
        float aa = b2[t];
        for (int k = 0; k < HF; k++) aa += zz[k] * W2[(size_t)k * C_ + t];
        logits[t] = aa;
    }
    __syncthreads();
    if (t == 0) {
        float mx = -1e30f;
        for (int i = 0; i < C_; i++) mx = fmaxf(mx, logits[i]);
        float s = 0.f;
        for (int i = 0; i < C_; i++) s += expf(logits[i] - mx);
        lse_s = mx + logf(s);
    }
    __syncthreads();
    if (t < C_) out1[(size_t)gid * C_ + t] = logits[t] - lse_s;
    if (t < D_) {
        float aa = b4[t];
        for (int k = 0; k < HF; k++) aa += zz[k] * W4[(size_t)k * D_ + t];
        out3[(size_t)gid * D_ + t] = aa;
    }
}

extern "C" void kernel_launch(void* const* d_in, const int* in_sizes, int n_in,
                              void* d_out, int out_size, void* d_ws, size_t ws_size,
                              hipStream_t stream)
{
    const float* x      = (const float*)d_in[0];
    const int*   ei     = (const int*)d_in[1];
    const int*   batch  = (const int*)d_in[2];
    const float* degree = (const float*)d_in[3];
    const float* eps1   = (const float*)d_in[4];
    const float* W1a    = (const float*)d_in[5];
    const float* b1a    = (const float*)d_in[6];
    const float* W1b    = (const float*)d_in[7];
    const float* b1b    = (const float*)d_in[8];
    const float* g1     = (const float*)d_in[9];
    const float* be1    = (const float*)d_in[10];
    const float* eps2   = (const float*)d_in[11];
    const float* W2a    = (const float*)d_in[12];
    const float* b2a    = (const float*)d_in[13];
    const float* W2b    = (const float*)d_in[14];
    const float* b2b    = (const float*)d_in[15];
    const float* g2     = (const float*)d_in[16];
    const float* be2    = (const float*)d_in[17];
    const float* Wlin1  = (const float*)d_in[18];
    const float* blin1  = (const float*)d_in[19];
    const float* Wlin2  = (const float*)d_in[20];
    const float* blin2  = (const float*)d_in[21];
    const float* Wlin4  = (const float*)d_in[22];
    const float* blin4  = (const float*)d_in[23];
    const float* Wloss  = (const float*)d_in[24];
    const float* bloss  = (const float*)d_in[25];

    const int N  = in_sizes[0] / HF;
    const int E  = in_sizes[1] / 2;
    const int C_ = in_sizes[21];
    const int D_ = in_sizes[23];
    const int Gn = (out_size - 1) / (C_ + D_);
    const int NB = (N + BSZ - 1) >> BSH;

    const int* src = ei;
    const int* dst = ei + E;

    size_t NH = (size_t)N * HF;
    char* p = (char*)d_ws;
    unsigned short* xb  = (unsigned short*)p; p += NH * 2;
    unsigned short* U   = (unsigned short*)p; p += NH * 2;
    unsigned short* Hp1 = (unsigned short*)p; p += NH * 2;
    unsigned short* Hp2 = (unsigned short*)p; p += NH * 2;
    unsigned char*  x8  = (unsigned char*)p; p += NH + HF; // fp8 shadow of x (+zero row N)
    unsigned char*  h8  = (unsigned char*)p; p += NH + HF; // fp8 shadow of Hp1 (+zero row N)
    unsigned short* WtAll = (unsigned short*)p; p += 4 * 16384 * 2;
    float* S1a  = (float*)p; p += HF * 4;     // [S1a S2a S1b S2b] contiguous
    float* S2a  = (float*)p; p += HF * 4;
    float* S1b  = (float*)p; p += HF * 4;
    float* S2b  = (float*)p; p += HF * 4;
    int* gstart = (int*)p; p += (Gn + 1) * 4;
    int* boff   = (int*)p; p += (NBMAX + 1) * 4;
    int* bcur   = (int*)p; p += NBMAX * 4;
    int* tot    = (int*)p; p += NBMAX * 4;
    int* off    = (int*)p; p += (N + 1) * 4;
    int* esrc   = (int*)p; p += E * 4;
    unsigned* ebuf = (unsigned*)p; p += E * 4;

    unsigned short* Wt1a = WtAll;
    unsigned short* Wt1b = WtAll + 16384;
    unsigned short* Wt2a = WtAll + 32768;
    unsigned short* Wt2b = WtAll + 49152;

    float* out1 = (float*)d_out;
    float* out3 = out1 + (size_t)Gn * C_;
    float* outm = out3 + (size_t)Gn * D_;

    int nchunks  = (int)(NH / 8);
    int castBlk  = (nchunks + 255) / 256;
    int nBlocks  = (N + 255) / 256;
    int gatherBlk = (N * 16 + 255) / 256;
    int ntiles   = (N + 15) / 16;
    int gemmBlk  = 1024;                      // persistent, ~3-4 blocks/CU
    if (gemmBlk > ntiles) gemmBlk = ntiles;
    int chunkH   = (E + HB - 1) / HB;
    float invN = 1.0f / (float)N;

    int initBlk = castBlk + 4 + HB + nBlocks + 1;

    // 0. zero bucket totals (accumulated by init_all's histogram phase)
    hipMemsetAsync(tot, 0, (size_t)NB * sizeof(int), stream);
    // 1. mega-init
    init_all<<<initBlk, 256, 0, stream>>>(x, xb, x8, h8, castBlk, nchunks,
                                          W1a, W1b, W2a, W2b, WtAll,
                                          dst, tot, E, chunkH,
                                          batch, gstart, N, Gn, nBlocks,
                                          S1a, outm);
    // 2. bucket totals -> offsets + cursors (tiny scan)
    scanp<<<1, 256, 0, stream>>>(tot, boff, bcur, NB, E);
    // 3. bin edges
    bucket_bin<<<HB, 256, 0, stream>>>(src, dst, bcur, ebuf, E, NB, chunkH);
    // 4. per-bucket CSR fill
    bucket_fill<<<NB, 256, 0, stream>>>(ebuf, boff, off, esrc, N, NB, E);
    // 5-6. layer 1 (r7 gather from fp8 x8; prefetched gemm emits Hp1 + h8)
    gather_u<false><<<gatherBlk, 256, 0, stream>>>(xb, x8, off, esrc, eps1,
                                                   nullptr, nullptr, nullptr, nullptr, 0.f, U, N);
    gemm2L<<<gemmBlk, 256, 0, stream>>>(U, Wt1a, b1a, Wt1b, b1b, Hp1, h8, S1a, S2a, N);
    // 7-8. layer 2 (r7 gather from fp8 h8; BN1 finalize inline)
    gather_u<true><<<gatherBlk, 256, 0, stream>>>(Hp1, h8, off, esrc, eps2,
                                                  S1a, S2a, g1, be1, invN, U, N);
    gemm2L<<<gemmBlk, 256, 0, stream>>>(U, Wt2a, b2a, Wt2b, b2b, Hp2, nullptr, S1b, S2b, N);
    // 9. tail
    pool_tail<<<Gn, 512, 0, stream>>>(Hp2, S1b, S2b, g2, be2, invN, gstart,
                                      Wlin1, blin1, Wloss, bloss, degree,
                                      Wlin2, blin2, Wlin4, blin4,
                                      out1, out3, outm, C_, D_);
}

// Round 12
// 433.521 us; speedup vs baseline: 1.4229x; 1.0004x over previous
//
#include <hip/hip_runtime.h>
#include <hip/hip_bf16.h>

#define HF 128   // feature/hidden dim (F == H == 128)
#define BSH 8    // bucket shift: 256 nodes per bucket
#define BSZ 256
#define NBMAX 1024
#define FCAP 8192
#define HB 512   // histogram/bin blocks

typedef __attribute__((ext_vector_type(8))) short bf16x8;
typedef __attribute__((ext_vector_type(4))) float f32x4;
typedef __attribute__((ext_vector_type(2))) float f32x2;

__device__ inline float bflo(unsigned u) { return __uint_as_float(u << 16); }
__device__ inline float bfhi(unsigned u) { return __uint_as_float(u & 0xffff0000u); }
__device__ inline unsigned short f2bf(float f) {
    unsigned u = __float_as_uint(f);
    unsigned r = (u + 0x7fffu + ((u >> 16) & 1u)) >> 16;
    return (unsigned short)r;
}
__device__ inline unsigned pack2(float a, float b) {
    return (unsigned)f2bf(a) | ((unsigned)f2bf(b) << 16);
}
// pack 8 floats -> 8 fp8 e4m3 (uint2)
__device__ inline uint2 pk8_fp8(const float* v) {
    int a = __builtin_amdgcn_cvt_pk_fp8_f32(v[0], v[1], 0, 0);
    a = __builtin_amdgcn_cvt_pk_fp8_f32(v[2], v[3], a, 1);
    int b = __builtin_amdgcn_cvt_pk_fp8_f32(v[4], v[5], 0, 0);
    b = __builtin_amdgcn_cvt_pk_fp8_f32(v[6], v[7], b, 1);
    uint2 r; r.x = (unsigned)a; r.y = (unsigned)b;
    return r;
}

// ============ mega-init: cast_x(bf16+fp8) | cast_wt | hist | bounds | zero ===
__global__ __launch_bounds__(256) void init_all(
    const float* __restrict__ x, unsigned short* __restrict__ xb,
    unsigned char* __restrict__ x8, unsigned char* __restrict__ h8,
    int castBlk, int nchunks,
    const float* __restrict__ w0, const float* __restrict__ w1,
    const float* __restrict__ w2, const float* __restrict__ w3,
    unsigned short* __restrict__ WtAll,
    const int* __restrict__ dst, int* __restrict__ tot, int E, int chunkH,
    const int* __restrict__ batch, int* __restrict__ gstart, int N, int Gn, int nBlocks,
    float* __restrict__ Szero, float* __restrict__ outm)
{
    __shared__ int lh[NBMAX];
    int b = blockIdx.x;
    int t = threadIdx.x;
    if (b < castBlk) {                       // ---- cast x -> bf16 + fp8
        int i = b * 256 + t;
        if (i < nchunks) {
            float4 a = ((const float4*)x)[2 * i];
            float4 c = ((const float4*)x)[2 * i + 1];
            uint4 o;
            o.x = pack2(a.x, a.y); o.y = pack2(a.z, a.w);
            o.z = pack2(c.x, c.y); o.w = pack2(c.z, c.w);
            ((uint4*)xb)[i] = o;
            float v[8] = {a.x, a.y, a.z, a.w, c.x, c.y, c.z, c.w};
            ((uint2*)x8)[i] = pk8_fp8(v);
        }
        return;
    }
    b -= castBlk;
    if (b < 4) {                             // ---- fragment-order cast weights
        const float* W = (b == 0) ? w0 : (b == 1) ? w1 : (b == 2) ? w2 : w3;
        unsigned short* O = WtAll + b * 16384;
        for (int idx = t; idx < 16384; idx += 256) {
            int j    = idx & 7;
            int lane = (idx >> 3) & 63;
            int fk   = idx >> 9;             // 0..31
            int kk = fk & 3, nt = fk >> 2;
            int m = lane & 15, quad = lane >> 4;
            int ncol = nt * 16 + m;
            int krow = kk * 32 + quad * 8 + j;
            O[idx] = f2bf(W[krow * 128 + ncol]);
        }
        return;
    }
    b -= 4;
    if (b < HB) {                            // ---- histogram partials -> global tot
        int NBl = (N + BSZ - 1) >> BSH;
        for (int i = t; i < NBl; i += 256) lh[i] = 0;
        __syncthreads();
        int beg = b * chunkH;
        int end = min(E, beg + chunkH);
        for (int e = beg + t; e < end; e += 256)
            atomicAdd(&lh[dst[e] >> BSH], 1);
        __syncthreads();
        for (int i = t; i < NBl; i += 256) {
            int c = lh[i];
            if (c) atomicAdd(&tot[i], c);
        }
        return;
    }
    b -= HB;
    if (b < nBlocks) {                       // ---- graph bounds
        int i = b * 256 + t;
        if (i >= N) return;
        int bi = batch[i];
        int bp = (i == 0) ? -1 : batch[i - 1];
        for (int g = bp + 1; g <= bi; g++) gstart[g] = i;
        if (i == N - 1)
            for (int g = bi + 1; g <= Gn; g++) gstart[g] = N;
        return;
    }
    if (t < 2 * HF) { Szero[t] = 0.f; Szero[t + 2 * HF] = 0.f; }
    if (t == 0) outm[0] = 0.f;
    // zero-pad row at index N for both fp8 tables (harmless; kept for safety)
    if (t < 32) ((unsigned*)(x8 + (size_t)N * HF))[t] = 0u;
    else if (t < 64) ((unsigned*)(h8 + (size_t)N * HF))[t - 32] = 0u;
}

// ============ scan: bucket totals (tiny) -> boff/bcur ========================
__global__ void scanp(const int* __restrict__ tot, int* __restrict__ boff,
                      int* __restrict__ bcur, int NB, int E)
{
    __shared__ int part[256];
    int t = threadIdx.x;
    int v[4];
    int s = 0;
#pragma unroll
    for (int i = 0; i < 4; i++) {
        int idx = t * 4 + i;
        v[i] = (idx < NB) ? tot[idx] : 0;
        s += v[i];
    }
    part[t] = s;
    __syncthreads();
    for (int o = 1; o < 256; o <<= 1) {
        int y = (t >= o) ? part[t - o] : 0;
        __syncthreads();
        part[t] += y;
        __syncthreads();
    }
    int base = part[t] - s;
#pragma unroll
    for (int i = 0; i < 4; i++) {
        int idx = t * 4 + i;
        if (idx < NB) { boff[idx] = base; bcur[idx] = base; base += v[i]; }
    }
    if (t == 0) boff[NB] = E;
}

// ============ bin edges =====================================================
__global__ __launch_bounds__(256) void bucket_bin(
    const int* __restrict__ src, const int* __restrict__ dst,
    int* __restrict__ bcur, unsigned* __restrict__ ebuf, int E, int NB, int chunkH)
{
    __shared__ int lh[NBMAX];
    int t = threadIdx.x;
    for (int i = t; i < NB; i += 256) lh[i] = 0;
    __syncthreads();
    int beg = blockIdx.x * chunkH;
    int end = min(E, beg + chunkH);
    for (int e = beg + t; e < end; e += 256)
        atomicAdd(&lh[dst[e] >> BSH], 1);
    __syncthreads();
    for (int i = t; i < NB; i += 256) {
        int c = lh[i];
        lh[i] = c ? atomicAdd(&bcur[i], c) : 0;
    }
    __syncthreads();
    for (int e = beg + t; e < end; e += 256) {
        int d = dst[e];
        int b = d >> BSH;
        int pos = atomicAdd(&lh[b], 1);
        ebuf[pos] = ((unsigned)src[e] << BSH) | (unsigned)(d & (BSZ - 1));
    }
}

// ============ per-bucket fill ================================================
__global__ __launch_bounds__(256) void bucket_fill(
    const unsigned* __restrict__ ebuf, const int* __restrict__ boff,
    int* __restrict__ off, int* __restrict__ esrc, int N, int NB, int E)
{
    __shared__ int deg[BSZ];
    __shared__ int pref[BSZ];
    __shared__ int lcur[BSZ];
    __shared__ int lsr[FCAP];
    int b = blockIdx.x;
    int t = threadIdx.x;
    int segBeg = boff[b], segEnd = boff[b + 1];
    int segLen = segEnd - segBeg;
    int node0 = b << BSH;
    deg[t] = 0;
    __syncthreads();
    for (int i = segBeg + t; i < segEnd; i += 256)
        atomicAdd(&deg[ebuf[i] & (BSZ - 1)], 1);
    __syncthreads();
    int dv = deg[t];
    pref[t] = dv;
    __syncthreads();
    for (int o = 1; o < 256; o <<= 1) {
        int y = (t >= o) ? pref[t - o] : 0;
        __syncthreads();
        pref[t] += y;
        __syncthreads();
    }
    int excl = pref[t] - dv;
    int node = node0 + t;
    if (node < N) off[node] = segBeg + excl;
    lcur[t] = excl;
    if (b == NB - 1 && t == 0) off[N] = E;
    __syncthreads();
    if (segLen <= FCAP) {
        for (int i = segBeg + t; i < segEnd; i += 256) {
            unsigned v = ebuf[i];
            int slot = atomicAdd(&lcur[v & (BSZ - 1)], 1);
            lsr[slot] = (int)(v >> BSH);
        }
        __syncthreads();
        for (int i = t; i < segLen; i += 256) esrc[segBeg + i] = lsr[i];
    } else {
        for (int i = segBeg + t; i < segEnd; i += 256) {
            unsigned v = ebuf[i];
            int slot = atomicAdd(&lcur[v & (BSZ - 1)], 1);
            esrc[segBeg + slot] = (int)(v >> BSH);
        }
    }
}

// ============ gather: pipelined neighbor loads from fp8 table ===============
// Round-7 body (measured best: 48.2us): 16-deep load batch into registers,
// cndmask tail-zeroing, (256,4). r8 diet regressed 9%; r9 (256,8) spilled.
template <bool FOLD>
__global__ __launch_bounds__(256, 4) void gather_u(
    const unsigned short* __restrict__ xb, const unsigned char* __restrict__ x8,
    const int* __restrict__ off, const int* __restrict__ esrc,
    const float* __restrict__ epsp,
    const float* __restrict__ S1, const float* __restrict__ S2,
    const float* __restrict__ gamma, const float* __restrict__ beta, float invN,
    unsigned short* __restrict__ Uo, int N)
{
    __shared__ float lsc[HF], lsh[HF];
    int tid = threadIdx.x;
    if (FOLD) {
        if (tid < HF) {
            float mu = S1[tid] * invN;
            float var = S2[tid] * invN - mu * mu;
            float rs = rsqrtf(var + 1e-5f);
            float sc = gamma[tid] * rs;
            lsc[tid] = sc;
            lsh[tid] = beta[tid] - mu * sc;
        }
        __syncthreads();
    }
    int lane16 = tid & 15;
    int node = (blockIdx.x * 256 + tid) >> 4;
    if (node >= N) return;
    int beg = off[node], end = off[node + 1];
    float acc[8] = {0.f, 0.f, 0.f, 0.f, 0.f, 0.f, 0.f, 0.f};
    const unsigned char* x8l = x8 + lane16 * 8;
    for (int j0 = beg; j0 < end; j0 += 16) {
        int myidx = (j0 + lane16 < end) ? esrc[j0 + lane16] : -1;
        uint2 pb[16];
#pragma unroll
        for (int t = 0; t < 16; t++) {
            int s = __shfl(myidx, t, 16);
            int sc = (s < 0) ? 0 : s;
            uint2 pv = *(const uint2*)(x8l + (size_t)sc * HF);
            if (s < 0) { pv.x = 0u; pv.y = 0u; }
            pb[t] = pv;
        }
#pragma unroll
        for (int t = 0; t < 16; t++) {
            f32x2 f0 = __builtin_amdgcn_cvt_pk_f32_fp8((int)pb[t].x, 0);
            f32x2 f1 = __builtin_amdgcn_cvt_pk_f32_fp8((int)pb[t].x, 1);
            f32x2 f2 = __builtin_amdgcn_cvt_pk_f32_fp8((int)pb[t].y, 0);
            f32x2 f3 = __builtin_amdgcn_cvt_pk_f32_fp8((int)pb[t].y, 1);
            acc[0] += f0.x; acc[1] += f0.y;
            acc[2] += f1.x; acc[3] += f1.y;
            acc[4] += f2.x; acc[5] += f2.y;
            acc[6] += f3.x; acc[7] += f3.y;
        }
    }
    float ep = 1.0f + epsp[0];
    uint4 xx = *(const uint4*)(xb + (size_t)node * HF + lane16 * 8);
    acc[0] += ep * bflo(xx.x); acc[1] += ep * bfhi(xx.x);
    acc[2] += ep * bflo(xx.y); acc[3] += ep * bfhi(xx.y);
    acc[4] += ep * bflo(xx.z); acc[5] += ep * bfhi(xx.z);
    acc[6] += ep * bflo(xx.w); acc[7] += ep * bfhi(xx.w);
    if (FOLD) {
        float cf = ep + (float)(end - beg);
        const float4 s0 = *(const float4*)(&lsc[lane16 * 8]);
        const float4 s1 = *(const float4*)(&lsc[lane16 * 8 + 4]);
        const float4 h0 = *(const float4*)(&lsh[lane16 * 8]);
        const float4 h1 = *(const float4*)(&lsh[lane16 * 8 + 4]);
        acc[0] = acc[0] * s0.x + h0.x * cf; acc[1] = acc[1] * s0.y + h0.y * cf;
        acc[2] = acc[2] * s0.z + h0.z * cf; acc[3] = acc[3] * s0.w + h0.w * cf;
        acc[4] = acc[4] * s1.x + h1.x * cf; acc[5] = acc[5] * s1.y + h1.y * cf;
        acc[6] = acc[6] * s1.z + h1.z * cf; acc[7] = acc[7] * s1.w + h1.w * cf;
    }
    uint4 o;
    o.x = pack2(acc[0], acc[1]); o.y = pack2(acc[2], acc[3]);
    o.z = pack2(acc[4], acc[5]); o.w = pack2(acc[6], acc[7]);
    *(uint4*)(Uo + (size_t)node * HF + lane16 * 8) = o;
}

// ====== persistent double-GEMM, REGISTER-RESIDENT weights + A prefetch ======
// (r7 structure + r11 prefetch; out of top-5 at <48us. Unchanged.)
__global__ __launch_bounds__(256, 3) void gemm2L(
    const unsigned short* __restrict__ U,
    const unsigned short* __restrict__ Wfa, const float* __restrict__ ba,
    const unsigned short* __restrict__ Wfb, const float* __restrict__ bb,
    unsigned short* __restrict__ out, unsigned char* __restrict__ out8,
    float* __restrict__ S1, float* __restrict__ S2, int n)
{
    __shared__ __align__(16) unsigned short lA[2048];   // 4 KB h1 exchange (16x128 swz)
    __shared__ __align__(16) unsigned short lB[2048];   // 4 KB h2 staging
    int tid = threadIdx.x;
    int w = tid >> 6, lane = tid & 63;
    int m = lane & 15, quad = lane >> 4;
    int swzA = (m & 7) << 3;
    int ntiles = (n + 15) >> 4;

    // ---- resident weight fragments: wave w -> nt in {2w, 2w+1}
    const bf16x8* __restrict__ Ba = (const bf16x8*)Wfa;
    const bf16x8* __restrict__ Bb = (const bf16x8*)Wfb;
    bf16x8 wa[2][4], wb[2][4];
#pragma unroll
    for (int q = 0; q < 2; q++) {
        int nt = 2 * w + q;
#pragma unroll
        for (int kk = 0; kk < 4; kk++) {
            wa[q][kk] = Ba[(((nt << 2) | kk) << 6) | lane];
            wb[q][kk] = Bb[(((nt << 2) | kk) << 6) | lane];
        }
    }
    float bav[2], bbv[2];
#pragma unroll
    for (int q = 0; q < 2; q++) {
        bav[q] = ba[(2 * w + q) * 16 + m];
        bbv[q] = bb[(2 * w + q) * 16 + m];
    }
    float csA[2] = {0.f, 0.f}, cqA[2] = {0.f, 0.f};

    // ---- prologue: load first tile's A fragments
    bf16x8 aF[4];
    int tile = blockIdx.x;
    if (tile < ntiles) {
        int ar = tile * 16 + m; if (ar >= n) ar = n - 1;
        const unsigned short* up = U + (size_t)ar * HF + quad * 8;
#pragma unroll
        for (int kk = 0; kk < 4; kk++) aF[kk] = *(const bf16x8*)(up + kk * 32);
    }

    for (; tile < ntiles; tile += gridDim.x) {
        int row0 = tile << 4;
        // ---- prefetch next tile's A fragments (reload current on last iter)
        bf16x8 aN[4];
        {
            int tn = tile + gridDim.x;
            int tl = (tn < ntiles) ? tn : tile;
            int ar = tl * 16 + m; if (ar >= n) ar = n - 1;
            const unsigned short* up = U + (size_t)ar * HF + quad * 8;
#pragma unroll
            for (int kk = 0; kk < 4; kk++) aN[kk] = *(const bf16x8*)(up + kk * 32);
        }

        // ---- GEMM1 quarter (8 MFMA)
        f32x4 acc[2];
#pragma unroll
        for (int q = 0; q < 2; q++) acc[q] = (f32x4){0.f, 0.f, 0.f, 0.f};
#pragma unroll
        for (int q = 0; q < 2; q++)
#pragma unroll
            for (int kk = 0; kk < 4; kk++)
                acc[q] = __builtin_amdgcn_mfma_f32_16x16x32_bf16(aF[kk], wa[q][kk], acc[q], 0, 0, 0);
        // relu+bias -> lA (column quarter, swizzled rows)
#pragma unroll
        for (int q = 0; q < 2; q++) {
            int col = (2 * w + q) * 16 + m;
#pragma unroll
            for (int r = 0; r < 4; r++) {
                int row = (quad << 2) | r;
                lA[(row << 7) | (col ^ ((row & 7) << 3))] =
                    f2bf(fmaxf(acc[q][r] + bav[q], 0.f));
            }
        }
        __syncthreads();
        // ---- full h1 rows for GEMM2 A-operand
        bf16x8 a2[4];
#pragma unroll
        for (int kk = 0; kk < 4; kk++)
            a2[kk] = *(const bf16x8*)(&lA[(m << 7) | (((kk << 5) | (quad << 3)) ^ swzA)]);
        // ---- GEMM2 quarter (8 MFMA)
#pragma unroll
        for (int q = 0; q < 2; q++) acc[q] = (f32x4){0.f, 0.f, 0.f, 0.f};
#pragma unroll
        for (int q = 0; q < 2; q++)
#pragma unroll
            for (int kk = 0; kk < 4; kk++)
                acc[q] = __builtin_amdgcn_mfma_f32_16x16x32_bf16(a2[kk], wb[q][kk], acc[q], 0, 0, 0);
        // ---- epilogue: relu+bias, reg-accumulated stats, restage to lB
#pragma unroll
        for (int q = 0; q < 2; q++) {
            int col = (2 * w + q) * 16 + m;
            float cs = 0.f, cq = 0.f;
#pragma unroll
            for (int r = 0; r < 4; r++) {
                int row = (quad << 2) | r;
                float v = fmaxf(acc[q][r] + bbv[q], 0.f);
                lB[(row << 7) | (col ^ ((row & 7) << 3))] = f2bf(v);
                if (row0 + row < n) { cs += v; cq += v * v; }
            }
            cs += __shfl_down(cs, 32); cs += __shfl_down(cs, 16);
            cq += __shfl_down(cq, 32); cq += __shfl_down(cq, 16);
            csA[q] += cs; cqA[q] += cq;
        }
        __syncthreads();
        // ---- coalesced store: 256 threads cover 16 rows x 16 chunks of 16B
        {
            int row = tid >> 4, c16 = tid & 15;
            int grow = row0 + row;
            if (grow < n) {
                uint4 v = *(const uint4*)(&lB[(row << 7) | ((c16 << 3) ^ ((row & 7) << 3))]);
                *(uint4*)(out + (size_t)grow * HF + (c16 << 3)) = v;
                if (out8) {
                    float f[8] = {bflo(v.x), bfhi(v.x), bflo(v.y), bfhi(v.y),
                                  bflo(v.z), bfhi(v.z), bflo(v.w), bfhi(v.w)};
                    *(uint2*)(out8 + (size_t)grow * HF + (c16 << 3)) = pk8_fp8(f);
                }
            }
        }
#pragma unroll
        for (int kk = 0; kk < 4; kk++) aF[kk] = aN[kk];
    }

    // ---- global stats: one atomic set per wave
    if (quad == 0) {
#pragma unroll
        for (int q = 0; q < 2; q++) {
            atomicAdd(&S1[(2 * w + q) * 16 + m], csA[q]);
            atomicAdd(&S2[(2 * w + q) * 16 + m], cqA[q]);
        }
    }
}

// ---- pool (BN2 inline) + lin1 + mse (atomic) + heads, one kernel/graph ----
// r11 PMC: 48us at 281 GB/s fetch = latency-bound row stream (1 load in
// flight per wave, 6-shfl dependent reduce between loads). Fix: 4x-unrolled
// row loop — 4 independent loads issued back-to-back, 4 interleaved
// reductions; tail rows zero-filled, mse terms predicated.
__global__ __launch_bounds__(512) void pool_tail(
    const unsigned short* __restrict__ h2raw,
    const float* __restrict__ S1, const float* __restrict__ S2,
    const float* __restrict__ gamma, const float* __restrict__ beta, float invN,
    const int* __restrict__ gstart, const float* __restrict__ W,
    const float* __restrict__ bias,
    const float* __restrict__ Wloss, const float* __restrict__ blossp,
    const float* __restrict__ degree,
    const float* __restrict__ W2, const float* __restrict__ b2,
    const float* __restrict__ W4, const float* __restrict__ b4,
    float* __restrict__ out1, float* __restrict__ out3,
    float* __restrict__ outm, int C_, int D_)
{
    __shared__ float lsc[HF], lsh[HF];
    __shared__ float red[8][HF];
    __shared__ float gv[HF];
    __shared__ float part[4][HF];
    __shared__ float wred[8];
    __shared__ float zz[HF];
    __shared__ float logits[16];
    __shared__ float lse_s;
    int gid = blockIdx.x;
    int t = threadIdx.x;
    if (t < HF) {
        float mu = S1[t] * invN;
        float var = S2[t] * invN - mu * mu;
        float rs = rsqrtf(var + 1e-5f);
        float sc = gamma[t] * rs;
        lsc[t] = sc;
        lsh[t] = beta[t] - mu * sc;
    }
    __syncthreads();
    int c2 = t & 63;
    int rg = t >> 6;
    int b = gstart[gid], e = gstart[gid + 1];
    float wla = lsc[2 * c2] * Wloss[2 * c2];
    float wlb = lsc[2 * c2 + 1] * Wloss[2 * c2 + 1];
    float c0l = lsh[2 * c2] * Wloss[2 * c2] + lsh[2 * c2 + 1] * Wloss[2 * c2 + 1];
    float bl = blossp[0];
    float s0 = 0.f, s1 = 0.f, macc = 0.f;
    for (int r = b + rg; r < e; r += 32) {
        int r1 = r + 8, r2 = r + 16, r3 = r + 24;
        bool k1 = r1 < e, k2 = r2 < e, k3 = r3 < e;
        // 4 independent row loads, issued back-to-back
        unsigned u0 = *(const unsigned*)(h2raw + (size_t)r * HF + c2 * 2);
        unsigned u1 = k1 ? *(const unsigned*)(h2raw + (size_t)r1 * HF + c2 * 2) : 0u;
        unsigned u2 = k2 ? *(const unsigned*)(h2raw + (size_t)r2 * HF + c2 * 2) : 0u;
        unsigned u3 = k3 ? *(const unsigned*)(h2raw + (size_t)r3 * HF + c2 * 2) : 0u;
        float a0 = bflo(u0), b0 = bfhi(u0);
        float a1 = bflo(u1), b1 = bfhi(u1);
        float a2 = bflo(u2), b2v = bfhi(u2);
        float a3 = bflo(u3), b3 = bfhi(u3);
        s0 += a0 + a1 + a2 + a3;             // zero-filled rows contribute 0
        s1 += b0 + b1 + b2v + b3;
        float m0 = a0 * wla + b0 * wlb + c0l;
        float m1 = a1 * wla + b1 * wlb + c0l;
        float m2 = a2 * wla + b2v * wlb + c0l;
        float m3 = a3 * wla + b3 * wlb + c0l;
#pragma unroll
        for (int o = 32; o > 0; o >>= 1) {   // 4 independent interleaved reduces
            m0 += __shfl_down(m0, o);
            m1 += __shfl_down(m1, o);
            m2 += __shfl_down(m2, o);
            m3 += __shfl_down(m3, o);
        }
        if (c2 == 0) {
            float d0 = m0 + bl - degree[r];
            macc += d0 * d0;
            if (k1) { float d = m1 + bl - degree[r1]; macc += d * d; }
            if (k2) { float d = m2 + bl - degree[r2]; macc += d * d; }
            if (k3) { float d = m3 + bl - degree[r3]; macc += d * d; }
        }
    }
    red[rg][c2 * 2] = s0;
    red[rg][c2 * 2 + 1] = s1;
    if (c2 == 0) wred[rg] = macc;
    __syncthreads();
    if (t < HF) {
        float s = red[0][t] + red[1][t] + red[2][t] + red[3][t]
                + red[4][t] + red[5][t] + red[6][t] + red[7][t];
        gv[t] = (e > b) ? lsc[t] * (s / (float)(e - b)) + lsh[t] : 0.f;
    }
    __syncthreads();
    int c = t & 127, kg = t >> 7;
    float a = 0.f;
#pragma unroll 8
    for (int k = kg * 32; k < kg * 32 + 32; k++) a += gv[k] * W[(size_t)k * HF + c];
    part[kg][c] = a;
    __syncthreads();
    if (t < HF) {
        float aa = part[0][t] + part[1][t] + part[2][t] + part[3][t] + bias[t];
        zz[t] = fmaxf(aa, 0.f);
    }
    if (t == 0) {
        float ps = wred[0] + wred[1] + wred[2] + wred[3]
                 + wred[4] + wred[5] + wred[6] + wred[7];
        atomicAdd(outm, ps * invN);
    }
    __syncthreads();
    if (t < C_) {
        float aa = b2[t];
        for (int k = 0; k < HF; k++) aa += zz[k] * W2[(size_t)k * C_ + t];
        logits[t] = aa;
    }
    __syncthreads();
    if (t == 0) {
        float mx = -1e30f;
        for (int i = 0; i < C_; i++) mx = fmaxf(mx, logits[i]);
        float s = 0.f;
        for (int i = 0; i < C_; i++) s += expf(logits[i] - mx);
        lse_s = mx + logf(s);
    }
    __syncthreads();
    if (t < C_) out1[(size_t)gid * C_ + t] = logits[t] - lse_s;
    if (t < D_) {
        float aa = b4[t];
        for (int k = 0; k < HF; k++) aa += zz[k] * W4[(size_t)k * D_ + t];
        out3[(size_t)gid * D_ + t] = aa;
    }
}

extern "C" void kernel_launch(void* const* d_in, const int* in_sizes, int n_in,
                              void* d_out, int out_size, void* d_ws, size_t ws_size,
                              hipStream_t stream)
{
    const float* x      = (const float*)d_in[0];
    const int*   ei     = (const int*)d_in[1];
    const int*   batch  = (const int*)d_in[2];
    const float* degree = (const float*)d_in[3];
    const float* eps1   = (const float*)d_in[4];
    const float* W1a    = (const float*)d_in[5];
    const float* b1a    = (const float*)d_in[6];
    const float* W1b    = (const float*)d_in[7];
    const float* b1b    = (const float*)d_in[8];
    const float* g1     = (const float*)d_in[9];
    const float* be1    = (const float*)d_in[10];
    const float* eps2   = (const float*)d_in[11];
    const float* W2a    = (const float*)d_in[12];
    const float* b2a    = (const float*)d_in[13];
    const float* W2b    = (const float*)d_in[14];
    const float* b2b    = (const float*)d_in[15];
    const float* g2     = (const float*)d_in[16];
    const float* be2    = (const float*)d_in[17];
    const float* Wlin1  = (const float*)d_in[18];
    const float* blin1  = (const float*)d_in[19];
    const float* Wlin2  = (const float*)d_in[20];
    const float* blin2  = (const float*)d_in[21];
    const float* Wlin4  = (const float*)d_in[22];
    const float* blin4  = (const float*)d_in[23];
    const float* Wloss  = (const float*)d_in[24];
    const float* bloss  = (const float*)d_in[25];

    const int N  = in_sizes[0] / HF;
    const int E  = in_sizes[1] / 2;
    const int C_ = in_sizes[21];
    const int D_ = in_sizes[23];
    const int Gn = (out_size - 1) / (C_ + D_);
    const int NB = (N + BSZ - 1) >> BSH;

    const int* src = ei;
    const int* dst = ei + E;

    size_t NH = (size_t)N * HF;
    char* p = (char*)d_ws;
    unsigned short* xb  = (unsigned short*)p; p += NH * 2;
    unsigned short* U   = (unsigned short*)p; p += NH * 2;
    unsigned short* Hp1 = (unsigned short*)p; p += NH * 2;
    unsigned short* Hp2 = (unsigned short*)p; p += NH * 2;
    unsigned char*  x8  = (unsigned char*)p; p += NH + HF; // fp8 shadow of x (+zero row N)
    unsigned char*  h8  = (unsigned char*)p; p += NH + HF; // fp8 shadow of Hp1 (+zero row N)
    unsigned short* WtAll = (unsigned short*)p; p += 4 * 16384 * 2;
    float* S1a  = (float*)p; p += HF * 4;     // [S1a S2a S1b S2b] contiguous
    float* S2a  = (float*)p; p += HF * 4;
    float* S1b  = (float*)p; p += HF * 4;
    float* S2b  = (float*)p; p += HF * 4;
    int* gstart = (int*)p; p += (Gn + 1) * 4;
    int* boff   = (int*)p; p += (NBMAX + 1) * 4;
    int* bcur   = (int*)p; p += NBMAX * 4;
    int* tot    = (int*)p; p += NBMAX * 4;
    int* off    = (int*)p; p += (N + 1) * 4;
    int* esrc   = (int*)p; p += E * 4;
    unsigned* ebuf = (unsigned*)p; p += E * 4;

    unsigned short* Wt1a = WtAll;
    unsigned short* Wt1b = WtAll + 16384;
    unsigned short* Wt2a = WtAll + 32768;
    unsigned short* Wt2b = WtAll + 49152;

    float* out1 = (float*)d_out;
    float* out3 = out1 + (size_t)Gn * C_;
    float* outm = out3 + (size_t)Gn * D_;

    int nchunks  = (int)(NH / 8);
    int castBlk  = (nchunks + 255) / 256;
    int nBlocks  = (N + 255) / 256;
    int gatherBlk = (N * 16 + 255) / 256;
    int ntiles   = (N + 15) / 16;
    int gemmBlk  = 1024;                      // persistent, ~3-4 blocks/CU
    if (gemmBlk > ntiles) gemmBlk = ntiles;
    int chunkH   = (E + HB - 1) / HB;
    float invN = 1.0f / (float)N;

    int initBlk = castBlk + 4 + HB + nBlocks + 1;

    // 0. zero bucket totals (accumulated by init_all's histogram phase)
    hipMemsetAsync(tot, 0, (size_t)NB * sizeof(int), stream);
    // 1. mega-init
    init_all<<<initBlk, 256, 0, stream>>>(x, xb, x8, h8, castBlk, nchunks,
                                          W1a, W1b, W2a, W2b, WtAll,
                                          dst, tot, E, chunkH,
                                          batch, gstart, N, Gn, nBlocks,
                                          S1a, outm);
    // 2. bucket totals -> offsets + cursors (tiny scan)
    scanp<<<1, 256, 0, stream>>>(tot, boff, bcur, NB, E);
    // 3. bin edges
    bucket_bin<<<HB, 256, 0, stream>>>(src, dst, bcur, ebuf, E, NB, chunkH);
    // 4. per-bucket CSR fill
    bucket_fill<<<NB, 256, 0, stream>>>(ebuf, boff, off, esrc, N, NB, E);
    // 5-6. layer 1 (r7 gather from fp8 x8; prefetched gemm emits Hp1 + h8)
    gather_u<false><<<gatherBlk, 256, 0, stream>>>(xb, x8, off, esrc, eps1,
                                                   nullptr, nullptr, nullptr, nullptr, 0.f, U, N);
    gemm2L<<<gemmBlk, 256, 0, stream>>>(U, Wt1a, b1a, Wt1b, b1b, Hp1, h8, S1a, S2a, N);
    // 7-8. layer 2 (r7 gather from fp8 h8; BN1 finalize inline)
    gather_u<true><<<gatherBlk, 256, 0, stream>>>(Hp1, h8, off, esrc, eps2,
                                                  S1a, S2a, g1, be1, invN, U, N);
    gemm2L<<<gemmBlk, 256, 0, stream>>>(U, Wt2a, b2a, Wt2b, b2b, Hp2, nullptr, S1b, S2b, N);
    // 9. tail
    pool_tail<<<Gn, 512, 0, stream>>>(Hp2, S1b, S2b, g2, be2, invN, gstart,
                                      Wlin1, blin1, Wloss, bloss, degree,
                                      Wlin2, blin2, Wlin4, blin4,
                                      out1, out3, outm, C_, D_);
}

// Round 13
// 416.305 us; speedup vs baseline: 1.4817x; 1.0414x over previous
//
#include <hip/hip_runtime.h>
#include <hip/hip_bf16.h>

#define HF 128   // feature/hidden dim (F == H == 128)
#define BSH 8    // bucket shift: 256 nodes per bucket
#define BSZ 256
#define NBMAX 1024
#define FCAP 8192
#define HB 512   // histogram/bin blocks

typedef __attribute__((ext_vector_type(8))) short bf16x8;
typedef __attribute__((ext_vector_type(4))) float f32x4;
typedef __attribute__((ext_vector_type(2))) float f32x2;

__device__ inline float bflo(unsigned u) { return __uint_as_float(u << 16); }
__device__ inline float bfhi(unsigned u) { return __uint_as_float(u & 0xffff0000u); }
__device__ inline unsigned short f2bf(float f) {
    unsigned u = __float_as_uint(f);
    unsigned r = (u + 0x7fffu + ((u >> 16) & 1u)) >> 16;
    return (unsigned short)r;
}
__device__ inline unsigned pack2(float a, float b) {
    return (unsigned)f2bf(a) | ((unsigned)f2bf(b) << 16);
}
// pack 8 floats -> 8 fp8 e4m3 (uint2)
__device__ inline uint2 pk8_fp8(const float* v) {
    int a = __builtin_amdgcn_cvt_pk_fp8_f32(v[0], v[1], 0, 0);
    a = __builtin_amdgcn_cvt_pk_fp8_f32(v[2], v[3], a, 1);
    int b = __builtin_amdgcn_cvt_pk_fp8_f32(v[4], v[5], 0, 0);
    b = __builtin_amdgcn_cvt_pk_fp8_f32(v[6], v[7], b, 1);
    uint2 r; r.x = (unsigned)a; r.y = (unsigned)b;
    return r;
}

// ============ mega-init: cast_x(bf16+fp8) | cast_wt | hist | bounds | zero ===
__global__ __launch_bounds__(256) void init_all(
    const float* __restrict__ x, unsigned short* __restrict__ xb,
    unsigned char* __restrict__ x8, unsigned char* __restrict__ h8,
    int castBlk, int nchunks,
    const float* __restrict__ w0, const float* __restrict__ w1,
    const float* __restrict__ w2, const float* __restrict__ w3,
    unsigned short* __restrict__ WtAll,
    const int* __restrict__ dst, int* __restrict__ tot, int E, int chunkH,
    const int* __restrict__ batch, int* __restrict__ gstart, int N, int Gn, int nBlocks,
    float* __restrict__ Szero, float* __restrict__ outm)
{
    __shared__ int lh[NBMAX];
    int b = blockIdx.x;
    int t = threadIdx.x;
    if (b < castBlk) {                       // ---- cast x -> bf16 + fp8
        int i = b * 256 + t;
        if (i < nchunks) {
            float4 a = ((const float4*)x)[2 * i];
            float4 c = ((const float4*)x)[2 * i + 1];
            uint4 o;
            o.x = pack2(a.x, a.y); o.y = pack2(a.z, a.w);
            o.z = pack2(c.x, c.y); o.w = pack2(c.z, c.w);
            ((uint4*)xb)[i] = o;
            float v[8] = {a.x, a.y, a.z, a.w, c.x, c.y, c.z, c.w};
            ((uint2*)x8)[i] = pk8_fp8(v);
        }
        return;
    }
    b -= castBlk;
    if (b < 4) {                             // ---- fragment-order cast weights
        const float* W = (b == 0) ? w0 : (b == 1) ? w1 : (b == 2) ? w2 : w3;
        unsigned short* O = WtAll + b * 16384;
        for (int idx = t; idx < 16384; idx += 256) {
            int j    = idx & 7;
            int lane = (idx >> 3) & 63;
            int fk   = idx >> 9;             // 0..31
            int kk = fk & 3, nt = fk >> 2;
            int m = lane & 15, quad = lane >> 4;
            int ncol = nt * 16 + m;
            int krow = kk * 32 + quad * 8 + j;
            O[idx] = f2bf(W[krow * 128 + ncol]);
        }
        return;
    }
    b -= 4;
    if (b < HB) {                            // ---- histogram partials -> global tot
        int NBl = (N + BSZ - 1) >> BSH;
        for (int i = t; i < NBl; i += 256) lh[i] = 0;
        __syncthreads();
        int beg = b * chunkH;
        int end = min(E, beg + chunkH);
        for (int e = beg + t; e < end; e += 256)
            atomicAdd(&lh[dst[e] >> BSH], 1);
        __syncthreads();
        for (int i = t; i < NBl; i += 256) {
            int c = lh[i];
            if (c) atomicAdd(&tot[i], c);
        }
        return;
    }
    b -= HB;
    if (b < nBlocks) {                       // ---- graph bounds
        int i = b * 256 + t;
        if (i >= N) return;
        int bi = batch[i];
        int bp = (i == 0) ? -1 : batch[i - 1];
        for (int g = bp + 1; g <= bi; g++) gstart[g] = i;
        if (i == N - 1)
            for (int g = bi + 1; g <= Gn; g++) gstart[g] = N;
        return;
    }
    if (t < 2 * HF) { Szero[t] = 0.f; Szero[t + 2 * HF] = 0.f; }
    if (t == 0) outm[0] = 0.f;
    // zero-pad row at index N for both fp8 tables (harmless; kept for safety)
    if (t < 32) ((unsigned*)(x8 + (size_t)N * HF))[t] = 0u;
    else if (t < 64) ((unsigned*)(h8 + (size_t)N * HF))[t - 32] = 0u;
}

// ============ scan: bucket totals (tiny) -> boff/bcur ========================
__global__ void scanp(const int* __restrict__ tot, int* __restrict__ boff,
                      int* __restrict__ bcur, int NB, int E)
{
    __shared__ int part[256];
    int t = threadIdx.x;
    int v[4];
    int s = 0;
#pragma unroll
    for (int i = 0; i < 4; i++) {
        int idx = t * 4 + i;
        v[i] = (idx < NB) ? tot[idx] : 0;
        s += v[i];
    }
    part[t] = s;
    __syncthreads();
    for (int o = 1; o < 256; o <<= 1) {
        int y = (t >= o) ? part[t - o] : 0;
        __syncthreads();
        part[t] += y;
        __syncthreads();
    }
    int base = part[t] - s;
#pragma unroll
    for (int i = 0; i < 4; i++) {
        int idx = t * 4 + i;
        if (idx < NB) { boff[idx] = base; bcur[idx] = base; base += v[i]; }
    }
    if (t == 0) boff[NB] = E;
}

// ============ bin edges =====================================================
__global__ __launch_bounds__(256) void bucket_bin(
    const int* __restrict__ src, const int* __restrict__ dst,
    int* __restrict__ bcur, unsigned* __restrict__ ebuf, int E, int NB, int chunkH)
{
    __shared__ int lh[NBMAX];
    int t = threadIdx.x;
    for (int i = t; i < NB; i += 256) lh[i] = 0;
    __syncthreads();
    int beg = blockIdx.x * chunkH;
    int end = min(E, beg + chunkH);
    for (int e = beg + t; e < end; e += 256)
        atomicAdd(&lh[dst[e] >> BSH], 1);
    __syncthreads();
    for (int i = t; i < NB; i += 256) {
        int c = lh[i];
        lh[i] = c ? atomicAdd(&bcur[i], c) : 0;
    }
    __syncthreads();
    for (int e = beg + t; e < end; e += 256) {
        int d = dst[e];
        int b = d >> BSH;
        int pos = atomicAdd(&lh[b], 1);
        ebuf[pos] = ((unsigned)src[e] << BSH) | (unsigned)(d & (BSZ - 1));
    }
}

// ============ per-bucket fill ================================================
__global__ __launch_bounds__(256) void bucket_fill(
    const unsigned* __restrict__ ebuf, const int* __restrict__ boff,
    int* __restrict__ off, int* __restrict__ esrc, int N, int NB, int E)
{
    __shared__ int deg[BSZ];
    __shared__ int pref[BSZ];
    __shared__ int lcur[BSZ];
    __shared__ int lsr[FCAP];
    int b = blockIdx.x;
    int t = threadIdx.x;
    int segBeg = boff[b], segEnd = boff[b + 1];
    int segLen = segEnd - segBeg;
    int node0 = b << BSH;
    deg[t] = 0;
    __syncthreads();
    for (int i = segBeg + t; i < segEnd; i += 256)
        atomicAdd(&deg[ebuf[i] & (BSZ - 1)], 1);
    __syncthreads();
    int dv = deg[t];
    pref[t] = dv;
    __syncthreads();
    for (int o = 1; o < 256; o <<= 1) {
        int y = (t >= o) ? pref[t - o] : 0;
        __syncthreads();
        pref[t] += y;
        __syncthreads();
    }
    int excl = pref[t] - dv;
    int node = node0 + t;
    if (node < N) off[node] = segBeg + excl;
    lcur[t] = excl;
    if (b == NB - 1 && t == 0) off[N] = E;
    __syncthreads();
    if (segLen <= FCAP) {
        for (int i = segBeg + t; i < segEnd; i += 256) {
            unsigned v = ebuf[i];
            int slot = atomicAdd(&lcur[v & (BSZ - 1)], 1);
            lsr[slot] = (int)(v >> BSH);
        }
        __syncthreads();
        for (int i = t; i < segLen; i += 256) esrc[segBeg + i] = lsr[i];
    } else {
        for (int i = segBeg + t; i < segEnd; i += 256) {
            unsigned v = ebuf[i];
            int slot = atomicAdd(&lcur[v & (BSZ - 1)], 1);
            esrc[segBeg + slot] = (int)(v >> BSH);
        }
    }
}

// ============ gather: pipelined neighbor loads from fp8 table ===============
// Round-7 body (measured best: 48.2us): 16-deep load batch into registers,
// cndmask tail-zeroing, (256,4). r8 diet regressed 9%; r9 (256,8) spilled.
template <bool FOLD>
__global__ __launch_bounds__(256, 4) void gather_u(
    const unsigned short* __restrict__ xb, const unsigned char* __restrict__ x8,
    const int* __restrict__ off, const int* __restrict__ esrc,
    const float* __restrict__ epsp,
    const float* __restrict__ S1, const float* __restrict__ S2,
    const float* __restrict__ gamma, const float* __restrict__ beta, float invN,
    unsigned short* __restrict__ Uo, int N)
{
    __shared__ float lsc[HF], lsh[HF];
    int tid = threadIdx.x;
    if (FOLD) {
        if (tid < HF) {
            float mu = S1[tid] * invN;
            float var = S2[tid] * invN - mu * mu;
            float rs = rsqrtf(var + 1e-5f);
            float sc = gamma[tid] * rs;
            lsc[tid] = sc;
            lsh[tid] = beta[tid] - mu * sc;
        }
        __syncthreads();
    }
    int lane16 = tid & 15;
    int node = (blockIdx.x * 256 + tid) >> 4;
    if (node >= N) return;
    int beg = off[node], end = off[node + 1];
    float acc[8] = {0.f, 0.f, 0.f, 0.f, 0.f, 0.f, 0.f, 0.f};
    const unsigned char* x8l = x8 + lane16 * 8;
    for (int j0 = beg; j0 < end; j0 += 16) {
        int myidx = (j0 + lane16 < end) ? esrc[j0 + lane16] : -1;
        uint2 pb[16];
#pragma unroll
        for (int t = 0; t < 16; t++) {
            int s = __shfl(myidx, t, 16);
            int sc = (s < 0) ? 0 : s;
            uint2 pv = *(const uint2*)(x8l + (size_t)sc * HF);
            if (s < 0) { pv.x = 0u; pv.y = 0u; }
            pb[t] = pv;
        }
#pragma unroll
        for (int t = 0; t < 16; t++) {
            f32x2 f0 = __builtin_amdgcn_cvt_pk_f32_fp8((int)pb[t].x, 0);
            f32x2 f1 = __builtin_amdgcn_cvt_pk_f32_fp8((int)pb[t].x, 1);
            f32x2 f2 = __builtin_amdgcn_cvt_pk_f32_fp8((int)pb[t].y, 0);
            f32x2 f3 = __builtin_amdgcn_cvt_pk_f32_fp8((int)pb[t].y, 1);
            acc[0] += f0.x; acc[1] += f0.y;
            acc[2] += f1.x; acc[3] += f1.y;
            acc[4] += f2.x; acc[5] += f2.y;
            acc[6] += f3.x; acc[7] += f3.y;
        }
    }
    float ep = 1.0f + epsp[0];
    uint4 xx = *(const uint4*)(xb + (size_t)node * HF + lane16 * 8);
    acc[0] += ep * bflo(xx.x); acc[1] += ep * bfhi(xx.x);
    acc[2] += ep * bflo(xx.y); acc[3] += ep * bfhi(xx.y);
    acc[4] += ep * bflo(xx.z); acc[5] += ep * bfhi(xx.z);
    acc[6] += ep * bflo(xx.w); acc[7] += ep * bfhi(xx.w);
    if (FOLD) {
        float cf = ep + (float)(end - beg);
        const float4 s0 = *(const float4*)(&lsc[lane16 * 8]);
        const float4 s1 = *(const float4*)(&lsc[lane16 * 8 + 4]);
        const float4 h0 = *(const float4*)(&lsh[lane16 * 8]);
        const float4 h1 = *(const float4*)(&lsh[lane16 * 8 + 4]);
        acc[0] = acc[0] * s0.x + h0.x * cf; acc[1] = acc[1] * s0.y + h0.y * cf;
        acc[2] = acc[2] * s0.z + h0.z * cf; acc[3] = acc[3] * s0.w + h0.w * cf;
        acc[4] = acc[4] * s1.x + h1.x * cf; acc[5] = acc[5] * s1.y + h1.y * cf;
        acc[6] = acc[6] * s1.z + h1.z * cf; acc[7] = acc[7] * s1.w + h1.w * cf;
    }
    uint4 o;
    o.x = pack2(acc[0], acc[1]); o.y = pack2(acc[2], acc[3]);
    o.z = pack2(acc[4], acc[5]); o.w = pack2(acc[6], acc[7]);
    *(uint4*)(Uo + (size_t)node * HF + lane16 * 8) = o;
}

// ====== persistent double-GEMM, REGISTER-RESIDENT weights + A prefetch ======
// (r7 structure + r11 prefetch; out of top-5 at <48us. Unchanged.)
__global__ __launch_bounds__(256, 3) void gemm2L(
    const unsigned short* __restrict__ U,
    const unsigned short* __restrict__ Wfa, const float* __restrict__ ba,
    const unsigned short* __restrict__ Wfb, const float* __restrict__ bb,
    unsigned short* __restrict__ out, unsigned char* __restrict__ out8,
    float* __restrict__ S1, float* __restrict__ S2, int n)
{
    __shared__ __align__(16) unsigned short lA[2048];   // 4 KB h1 exchange (16x128 swz)
    __shared__ __align__(16) unsigned short lB[2048];   // 4 KB h2 staging
    int tid = threadIdx.x;
    int w = tid >> 6, lane = tid & 63;
    int m = lane & 15, quad = lane >> 4;
    int swzA = (m & 7) << 3;
    int ntiles = (n + 15) >> 4;

    // ---- resident weight fragments: wave w -> nt in {2w, 2w+1}
    const bf16x8* __restrict__ Ba = (const bf16x8*)Wfa;
    const bf16x8* __restrict__ Bb = (const bf16x8*)Wfb;
    bf16x8 wa[2][4], wb[2][4];
#pragma unroll
    for (int q = 0; q < 2; q++) {
        int nt = 2 * w + q;
#pragma unroll
        for (int kk = 0; kk < 4; kk++) {
            wa[q][kk] = Ba[(((nt << 2) | kk) << 6) | lane];
            wb[q][kk] = Bb[(((nt << 2) | kk) << 6) | lane];
        }
    }
    float bav[2], bbv[2];
#pragma unroll
    for (int q = 0; q < 2; q++) {
        bav[q] = ba[(2 * w + q) * 16 + m];
        bbv[q] = bb[(2 * w + q) * 16 + m];
    }
    float csA[2] = {0.f, 0.f}, cqA[2] = {0.f, 0.f};

    // ---- prologue: load first tile's A fragments
    bf16x8 aF[4];
    int tile = blockIdx.x;
    if (tile < ntiles) {
        int ar = tile * 16 + m; if (ar >= n) ar = n - 1;
        const unsigned short* up = U + (size_t)ar * HF + quad * 8;
#pragma unroll
        for (int kk = 0; kk < 4; kk++) aF[kk] = *(const bf16x8*)(up + kk * 32);
    }

    for (; tile < ntiles; tile += gridDim.x) {
        int row0 = tile << 4;
        // ---- prefetch next tile's A fragments (reload current on last iter)
        bf16x8 aN[4];
        {
            int tn = tile + gridDim.x;
            int tl = (tn < ntiles) ? tn : tile;
            int ar = tl * 16 + m; if (ar >= n) ar = n - 1;
            const unsigned short* up = U + (size_t)ar * HF + quad * 8;
#pragma unroll
            for (int kk = 0; kk < 4; kk++) aN[kk] = *(const bf16x8*)(up + kk * 32);
        }

        // ---- GEMM1 quarter (8 MFMA)
        f32x4 acc[2];
#pragma unroll
        for (int q = 0; q < 2; q++) acc[q] = (f32x4){0.f, 0.f, 0.f, 0.f};
#pragma unroll
        for (int q = 0; q < 2; q++)
#pragma unroll
            for (int kk = 0; kk < 4; kk++)
                acc[q] = __builtin_amdgcn_mfma_f32_16x16x32_bf16(aF[kk], wa[q][kk], acc[q], 0, 0, 0);
        // relu+bias -> lA (column quarter, swizzled rows)
#pragma unroll
        for (int q = 0; q < 2; q++) {
            int col = (2 * w + q) * 16 + m;
#pragma unroll
            for (int r = 0; r < 4; r++) {
                int row = (quad << 2) | r;
                lA[(row << 7) | (col ^ ((row & 7) << 3))] =
                    f2bf(fmaxf(acc[q][r] + bav[q], 0.f));
            }
        }
        __syncthreads();
        // ---- full h1 rows for GEMM2 A-operand
        bf16x8 a2[4];
#pragma unroll
        for (int kk = 0; kk < 4; kk++)
            a2[kk] = *(const bf16x8*)(&lA[(m << 7) | (((kk << 5) | (quad << 3)) ^ swzA)]);
        // ---- GEMM2 quarter (8 MFMA)
#pragma unroll
        for (int q = 0; q < 2; q++) acc[q] = (f32x4){0.f, 0.f, 0.f, 0.f};
#pragma unroll
        for (int q = 0; q < 2; q++)
#pragma unroll
            for (int kk = 0; kk < 4; kk++)
                acc[q] = __builtin_amdgcn_mfma_f32_16x16x32_bf16(a2[kk], wb[q][kk], acc[q], 0, 0, 0);
        // ---- epilogue: relu+bias, reg-accumulated stats, restage to lB
#pragma unroll
        for (int q = 0; q < 2; q++) {
            int col = (2 * w + q) * 16 + m;
            float cs = 0.f, cq = 0.f;
#pragma unroll
            for (int r = 0; r < 4; r++) {
                int row = (quad << 2) | r;
                float v = fmaxf(acc[q][r] + bbv[q], 0.f);
                lB[(row << 7) | (col ^ ((row & 7) << 3))] = f2bf(v);
                if (row0 + row < n) { cs += v; cq += v * v; }
            }
            cs += __shfl_down(cs, 32); cs += __shfl_down(cs, 16);
            cq += __shfl_down(cq, 32); cq += __shfl_down(cq, 16);
            csA[q] += cs; cqA[q] += cq;
        }
        __syncthreads();
        // ---- coalesced store: 256 threads cover 16 rows x 16 chunks of 16B
        {
            int row = tid >> 4, c16 = tid & 15;
            int grow = row0 + row;
            if (grow < n) {
                uint4 v = *(const uint4*)(&lB[(row << 7) | ((c16 << 3) ^ ((row & 7) << 3))]);
                *(uint4*)(out + (size_t)grow * HF + (c16 << 3)) = v;
                if (out8) {
                    float f[8] = {bflo(v.x), bfhi(v.x), bflo(v.y), bfhi(v.y),
                                  bflo(v.z), bfhi(v.z), bflo(v.w), bfhi(v.w)};
                    *(uint2*)(out8 + (size_t)grow * HF + (c16 << 3)) = pk8_fp8(f);
                }
            }
        }
#pragma unroll
        for (int kk = 0; kk < 4; kk++) aF[kk] = aN[kk];
    }

    // ---- global stats: one atomic set per wave
    if (quad == 0) {
#pragma unroll
        for (int q = 0; q < 2; q++) {
            atomicAdd(&S1[(2 * w + q) * 16 + m], csA[q]);
            atomicAdd(&S2[(2 * w + q) * 16 + m], cqA[q]);
        }
    }
}

// ---- pool (BN2 inline) + lin1 + mse (atomic) + heads, one kernel/graph ----
// r12: row stream 4x-unrolled (r11 fix). This round: the serial tail matvecs
// (logits C=10, out3 D=32 — previously 128-deep serial FMA chains on <=32
// threads) are parallelized across all 8 waves: output o -> wave o%8, 2
// k-elems per lane, 6-step shfl reduce.
__global__ __launch_bounds__(512) void pool_tail(
    const unsigned short* __restrict__ h2raw,
    const float* __restrict__ S1, const float* __restrict__ S2,
    const float* __restrict__ gamma, const float* __restrict__ beta, float invN,
    const int* __restrict__ gstart, const float* __restrict__ W,
    const float* __restrict__ bias,
    const float* __restrict__ Wloss, const float* __restrict__ blossp,
    const float* __restrict__ degree,
    const float* __restrict__ W2, const float* __restrict__ b2,
    const float* __restrict__ W4, const float* __restrict__ b4,
    float* __restrict__ out1, float* __restrict__ out3,
    float* __restrict__ outm, int C_, int D_)
{
    __shared__ float lsc[HF], lsh[HF];
    __shared__ float red[8][HF];
    __shared__ float gv[HF];
    __shared__ float part[4][HF];
    __shared__ float wred[8];
    __shared__ float zz[HF];
    __shared__ float logits[16];
    __shared__ float lse_s;
    int gid = blockIdx.x;
    int t = threadIdx.x;
    if (t < HF) {
        float mu = S1[t] * invN;
        float var = S2[t] * invN - mu * mu;
        float rs = rsqrtf(var + 1e-5f);
        float sc = gamma[t] * rs;
        lsc[t] = sc;
        lsh[t] = beta[t] - mu * sc;
    }
    __syncthreads();
    int c2 = t & 63;
    int rg = t >> 6;
    int b = gstart[gid], e = gstart[gid + 1];
    float wla = lsc[2 * c2] * Wloss[2 * c2];
    float wlb = lsc[2 * c2 + 1] * Wloss[2 * c2 + 1];
    float c0l = lsh[2 * c2] * Wloss[2 * c2] + lsh[2 * c2 + 1] * Wloss[2 * c2 + 1];
    float bl = blossp[0];
    float s0 = 0.f, s1 = 0.f, macc = 0.f;
    for (int r = b + rg; r < e; r += 32) {
        int r1 = r + 8, r2 = r + 16, r3 = r + 24;
        bool k1 = r1 < e, k2 = r2 < e, k3 = r3 < e;
        // 4 independent row loads, issued back-to-back
        unsigned u0 = *(const unsigned*)(h2raw + (size_t)r * HF + c2 * 2);
        unsigned u1 = k1 ? *(const unsigned*)(h2raw + (size_t)r1 * HF + c2 * 2) : 0u;
        unsigned u2 = k2 ? *(const unsigned*)(h2raw + (size_t)r2 * HF + c2 * 2) : 0u;
        unsigned u3 = k3 ? *(const unsigned*)(h2raw + (size_t)r3 * HF + c2 * 2) : 0u;
        float a0 = bflo(u0), b0 = bfhi(u0);
        float a1 = bflo(u1), b1 = bfhi(u1);
        float a2 = bflo(u2), b2v = bfhi(u2);
        float a3 = bflo(u3), b3 = bfhi(u3);
        s0 += a0 + a1 + a2 + a3;             // zero-filled rows contribute 0
        s1 += b0 + b1 + b2v + b3;
        float m0 = a0 * wla + b0 * wlb + c0l;
        float m1 = a1 * wla + b1 * wlb + c0l;
        float m2 = a2 * wla + b2v * wlb + c0l;
        float m3 = a3 * wla + b3 * wlb + c0l;
#pragma unroll
        for (int o = 32; o > 0; o >>= 1) {   // 4 independent interleaved reduces
            m0 += __shfl_down(m0, o);
            m1 += __shfl_down(m1, o);
            m2 += __shfl_down(m2, o);
            m3 += __shfl_down(m3, o);
        }
        if (c2 == 0) {
            float d0 = m0 + bl - degree[r];
            macc += d0 * d0;
            if (k1) { float d = m1 + bl - degree[r1]; macc += d * d; }
            if (k2) { float d = m2 + bl - degree[r2]; macc += d * d; }
            if (k3) { float d = m3 + bl - degree[r3]; macc += d * d; }
        }
    }
    red[rg][c2 * 2] = s0;
    red[rg][c2 * 2 + 1] = s1;
    if (c2 == 0) wred[rg] = macc;
    __syncthreads();
    if (t < HF) {
        float s = red[0][t] + red[1][t] + red[2][t] + red[3][t]
                + red[4][t] + red[5][t] + red[6][t] + red[7][t];
        gv[t] = (e > b) ? lsc[t] * (s / (float)(e - b)) + lsh[t] : 0.f;
    }
    __syncthreads();
    int c = t & 127, kg = t >> 7;
    float a = 0.f;
#pragma unroll 8
    for (int k = kg * 32; k < kg * 32 + 32; k++) a += gv[k] * W[(size_t)k * HF + c];
    part[kg][c] = a;
    __syncthreads();
    if (t < HF) {
        float aa = part[0][t] + part[1][t] + part[2][t] + part[3][t] + bias[t];
        zz[t] = fmaxf(aa, 0.f);
    }
    if (t == 0) {
        float ps = wred[0] + wred[1] + wred[2] + wred[3]
                 + wred[4] + wred[5] + wred[6] + wred[7];
        atomicAdd(outm, ps * invN);
    }
    __syncthreads();
    // ---- wave-parallel head matvecs: output o -> wave o%8, 2 k/lane, shfl
    {
        int wv = t >> 6, ln = t & 63;
        int nout = C_ + D_;
        for (int o = wv; o < nout; o += 8) {
            int k = ln * 2;
            float z0 = zz[k], z1 = zz[k + 1];
            float pp;
            if (o < C_)
                pp = z0 * W2[(size_t)k * C_ + o] + z1 * W2[(size_t)(k + 1) * C_ + o];
            else {
                int d = o - C_;
                pp = z0 * W4[(size_t)k * D_ + d] + z1 * W4[(size_t)(k + 1) * D_ + d];
            }
#pragma unroll
            for (int off = 32; off > 0; off >>= 1) pp += __shfl_down(pp, off);
            if (ln == 0) {
                if (o < C_) logits[o] = pp + b2[o];
                else {
                    int d = o - C_;
                    out3[(size_t)gid * D_ + d] = pp + b4[d];
                }
            }
        }
    }
    __syncthreads();
    if (t == 0) {
        float mx = -1e30f;
        for (int i = 0; i < C_; i++) mx = fmaxf(mx, logits[i]);
        float s = 0.f;
        for (int i = 0; i < C_; i++) s += expf(logits[i] - mx);
        lse_s = mx + logf(s);
    }
    __syncthreads();
    if (t < C_) out1[(size_t)gid * C_ + t] = logits[t] - lse_s;
}

extern "C" void kernel_launch(void* const* d_in, const int* in_sizes, int n_in,
                              void* d_out, int out_size, void* d_ws, size_t ws_size,
                              hipStream_t stream)
{
    const float* x      = (const float*)d_in[0];
    const int*   ei     = (const int*)d_in[1];
    const int*   batch  = (const int*)d_in[2];
    const float* degree = (const float*)d_in[3];
    const float* eps1   = (const float*)d_in[4];
    const float* W1a    = (const float*)d_in[5];
    const float* b1a    = (const float*)d_in[6];
    const float* W1b    = (const float*)d_in[7];
    const float* b1b    = (const float*)d_in[8];
    const float* g1     = (const float*)d_in[9];
    const float* be1    = (const float*)d_in[10];
    const float* eps2   = (const float*)d_in[11];
    const float* W2a    = (const float*)d_in[12];
    const float* b2a    = (const float*)d_in[13];
    const float* W2b    = (const float*)d_in[14];
    const float* b2b    = (const float*)d_in[15];
    const float* g2     = (const float*)d_in[16];
    const float* be2    = (const float*)d_in[17];
    const float* Wlin1  = (const float*)d_in[18];
    const float* blin1  = (const float*)d_in[19];
    const float* Wlin2  = (const float*)d_in[20];
    const float* blin2  = (const float*)d_in[21];
    const float* Wlin4  = (const float*)d_in[22];
    const float* blin4  = (const float*)d_in[23];
    const float* Wloss  = (const float*)d_in[24];
    const float* bloss  = (const float*)d_in[25];

    const int N  = in_sizes[0] / HF;
    const int E  = in_sizes[1] / 2;
    const int C_ = in_sizes[21];
    const int D_ = in_sizes[23];
    const int Gn = (out_size - 1) / (C_ + D_);
    const int NB = (N + BSZ - 1) >> BSH;

    const int* src = ei;
    const int* dst = ei + E;

    size_t NH = (size_t)N * HF;
    char* p = (char*)d_ws;
    unsigned short* xb  = (unsigned short*)p; p += NH * 2;
    unsigned short* U   = (unsigned short*)p; p += NH * 2;
    unsigned short* Hp1 = (unsigned short*)p; p += NH * 2;
    unsigned short* Hp2 = (unsigned short*)p; p += NH * 2;
    unsigned char*  x8  = (unsigned char*)p; p += NH + HF; // fp8 shadow of x (+zero row N)
    unsigned char*  h8  = (unsigned char*)p; p += NH + HF; // fp8 shadow of Hp1 (+zero row N)
    unsigned short* WtAll = (unsigned short*)p; p += 4 * 16384 * 2;
    float* S1a  = (float*)p; p += HF * 4;     // [S1a S2a S1b S2b] contiguous
    float* S2a  = (float*)p; p += HF * 4;
    float* S1b  = (float*)p; p += HF * 4;
    float* S2b  = (float*)p; p += HF * 4;
    int* gstart = (int*)p; p += (Gn + 1) * 4;
    int* boff   = (int*)p; p += (NBMAX + 1) * 4;
    int* bcur   = (int*)p; p += NBMAX * 4;
    int* tot    = (int*)p; p += NBMAX * 4;
    int* off    = (int*)p; p += (N + 1) * 4;
    int* esrc   = (int*)p; p += E * 4;
    unsigned* ebuf = (unsigned*)p; p += E * 4;

    unsigned short* Wt1a = WtAll;
    unsigned short* Wt1b = WtAll + 16384;
    unsigned short* Wt2a = WtAll + 32768;
    unsigned short* Wt2b = WtAll + 49152;

    float* out1 = (float*)d_out;
    float* out3 = out1 + (size_t)Gn * C_;
    float* outm = out3 + (size_t)Gn * D_;

    int nchunks  = (int)(NH / 8);
    int castBlk  = (nchunks + 255) / 256;
    int nBlocks  = (N + 255) / 256;
    int gatherBlk = (N * 16 + 255) / 256;
    int ntiles   = (N + 15) / 16;
    int gemmBlk  = 1024;                      // persistent, ~3-4 blocks/CU
    if (gemmBlk > ntiles) gemmBlk = ntiles;
    int chunkH   = (E + HB - 1) / HB;
    float invN = 1.0f / (float)N;

    int initBlk = castBlk + 4 + HB + nBlocks + 1;

    // 0. zero bucket totals (accumulated by init_all's histogram phase)
    hipMemsetAsync(tot, 0, (size_t)NB * sizeof(int), stream);
    // 1. mega-init
    init_all<<<initBlk, 256, 0, stream>>>(x, xb, x8, h8, castBlk, nchunks,
                                          W1a, W1b, W2a, W2b, WtAll,
                                          dst, tot, E, chunkH,
                                          batch, gstart, N, Gn, nBlocks,
                                          S1a, outm);
    // 2. bucket totals -> offsets + cursors (tiny scan)
    scanp<<<1, 256, 0, stream>>>(tot, boff, bcur, NB, E);
    // 3. bin edges
    bucket_bin<<<HB, 256, 0, stream>>>(src, dst, bcur, ebuf, E, NB, chunkH);
    // 4. per-bucket CSR fill
    bucket_fill<<<NB, 256, 0, stream>>>(ebuf, boff, off, esrc, N, NB, E);
    // 5-6. layer 1 (r7 gather from fp8 x8; prefetched gemm emits Hp1 + h8)
    gather_u<false><<<gatherBlk, 256, 0, stream>>>(xb, x8, off, esrc, eps1,
                                                   nullptr, nullptr, nullptr, nullptr, 0.f, U, N);
    gemm2L<<<gemmBlk, 256, 0, stream>>>(U, Wt1a, b1a, Wt1b, b1b, Hp1, h8, S1a, S2a, N);
    // 7-8. layer 2 (r7 gather from fp8 h8; BN1 finalize inline)
    gather_u<true><<<gatherBlk, 256, 0, stream>>>(Hp1, h8, off, esrc, eps2,
                                                  S1a, S2a, g1, be1, invN, U, N);
    gemm2L<<<gemmBlk, 256, 0, stream>>>(U, Wt2a, b2a, Wt2b, b2b, Hp2, nullptr, S1b, S2b, N);
    // 9. tail
    pool_tail<<<Gn, 512, 0, stream>>>(Hp2, S1b, S2b, g2, be2, invN, gstart,
                                      Wlin1, blin1, Wloss, bloss, degree,
                                      Wlin2, blin2, Wlin4, blin4,
                                      out1, out3, outm, C_, D_);
}